// Round 2
// baseline (3060.688 us; speedup 1.0000x reference)
//
#include <hip/hip_runtime.h>

typedef __attribute__((ext_vector_type(8))) short bf16x8;
typedef __attribute__((ext_vector_type(4))) float f32x4;
typedef unsigned short u16;

// ---------- helpers ----------
__device__ __forceinline__ u16 f2bf(float f) {
  union { float f; unsigned u; } v; v.f = f;
  unsigned r = v.u + 0x7fffu + ((v.u >> 16) & 1u);
  return (u16)(r >> 16);
}
__device__ __forceinline__ float bf2f(u16 h) {
  union { unsigned u; float f; } v; v.u = ((unsigned)h) << 16;
  return v.f;
}
__device__ __forceinline__ void split8(const f32x4 v0, const f32x4 v1, bf16x8 &hi, bf16x8 &lo) {
#pragma unroll
  for (int e = 0; e < 4; ++e) {
    u16 h0 = f2bf(v0[e]);
    hi[e] = (short)h0;
    lo[e] = (short)f2bf(v0[e] - bf2f(h0));
    u16 h1 = f2bf(v1[e]);
    hi[4 + e] = (short)h1;
    lo[4 + e] = (short)f2bf(v1[e] - bf2f(h1));
  }
}
__device__ __forceinline__ float sigm(float x) { return 1.f / (1.f + __expf(-x)); }
__device__ __forceinline__ float tanhf_(float x) { return 1.f - 2.f / (__expf(2.f * x) + 1.f); }

// ---------- K0: Wih (f|b concat [2048][256]) and W_emit ([16][512], rows>=9 zero) -> bf16 hi/lo ----------
__global__ __launch_bounds__(256) void k_prep_w(const float* __restrict__ wf, const float* __restrict__ wb,
                                                const float* __restrict__ we,
                                                u16* __restrict__ wihh, u16* __restrict__ wihl,
                                                u16* __restrict__ weh, u16* __restrict__ wel) {
  int i = blockIdx.x * 256 + threadIdx.x;
  float v; u16 *dh, *dl; int o;
  if (i < 524288) {
    int g = i >> 8, k = i & 255;
    v = (g < 1024) ? wf[g * 256 + k] : wb[(g - 1024) * 256 + k];
    dh = wihh; dl = wihl; o = i;
  } else {
    int j = i - 524288;
    int r = j >> 9, k = j & 511;
    v = (r < 9) ? we[r * 512 + k] : 0.f;
    dh = weh; dl = wel; o = j;
  }
  u16 hh = f2bf(v);
  dh[o] = hh; dl[o] = f2bf(v - bf2f(hh));
}

// ---------- K1: chunked input GEMM ----------
// xw[dir][b][sl][1024] for steps sg = c0step..c0step+S-1 (fwd t=sg, bwd t=127-sg).
// grid (4*S, 8, 2), block 256: 4 waves x 16-row m-tiles, 8 n-tiles of 16.
__global__ __launch_bounds__(256) void k_gemm_in(const int* __restrict__ ix,
    const float* __restrict__ emb,
    const u16* __restrict__ wh, const u16* __restrict__ wl,
    const float* __restrict__ bf_, const float* __restrict__ bb_,
    float* __restrict__ xw, int c0step, int S, int logS) {
  int w = threadIdx.x >> 6, l = threadIdx.x & 63;
  int la = l & 15, lk = (l >> 4) * 8;
  int dir = blockIdx.z;
  int m0 = blockIdx.x * 64 + w * 16;
  int n0 = blockIdx.y * 128;
  int mA = m0 + la;
  int bA = mA >> logS, slA = mA & (S - 1);
  int sg = c0step + slA;
  int tA = dir ? (127 - sg) : sg;
  const float* erow = emb + (long)ix[bA * 128 + tA] * 256;
  f32x4 acc[8];
#pragma unroll
  for (int i = 0; i < 8; ++i) acc[i] = (f32x4){0.f, 0.f, 0.f, 0.f};
#pragma unroll
  for (int ks = 0; ks < 8; ++ks) {
    int k = ks * 32 + lk;
    f32x4 v0 = *(const f32x4*)(erow + k);
    f32x4 v1 = *(const f32x4*)(erow + k + 4);
    bf16x8 ah, al;
    split8(v0, v1, ah, al);
#pragma unroll
    for (int nt = 0; nt < 8; ++nt) {
      int g = n0 + nt * 16 + la;
      long go = (long)(dir * 1024 + g) * 256 + k;
      bf16x8 bh = *(const bf16x8*)(wh + go);
      bf16x8 bl = *(const bf16x8*)(wl + go);
      acc[nt] = __builtin_amdgcn_mfma_f32_16x16x32_bf16(ah, bh, acc[nt], 0, 0, 0);
      acc[nt] = __builtin_amdgcn_mfma_f32_16x16x32_bf16(ah, bl, acc[nt], 0, 0, 0);
      acc[nt] = __builtin_amdgcn_mfma_f32_16x16x32_bf16(al, bh, acc[nt], 0, 0, 0);
    }
  }
  int mrb = m0 + (l >> 4) * 4;
#pragma unroll
  for (int nt = 0; nt < 8; ++nt) {
    int g = n0 + nt * 16 + la;
    float bias = (dir ? bb_ : bf_)[g];
#pragma unroll
    for (int r = 0; r < 4; ++r) {
      int m2 = mrb + r;
      int b2 = m2 >> logS, sl2 = m2 & (S - 1);
      xw[((long)(dir * 256 + b2) * S + sl2) * 1024 + g] = acc[nt][r] + bias;
    }
  }
}

// ---------- K2: BiLSTM recurrence (chunk of S steps) ----------
// 256 blocks = 2 dir x 16 batch-slices x 8 j-slices; Whh slice (hi+lo bf16) resident in LDS.
#define LW 264
__global__ __launch_bounds__(256) void k_lstm(
    const float* __restrict__ whh_f, const float* __restrict__ whh_b,
    const float* __restrict__ h0f, const float* __restrict__ c0f,
    const float* __restrict__ h0b, const float* __restrict__ c0b,
    const float* __restrict__ xw,
    float* __restrict__ hf, float* __restrict__ hb,
    float* __restrict__ cstate, unsigned* __restrict__ flags,
    int s0, int S, int first, int last) {
  __shared__ u16 wlh[128 * LW];
  __shared__ u16 wll[128 * LW];
  __shared__ float gl[16 * 132];
  int bid = blockIdx.x;
  int js = (bid >> 3) & 7;
  int G = ((bid >> 6) << 3) | (bid & 7);   // group id; members share blockIdx%8 (same XCD heuristic)
  int dir = G >> 4, bs = G & 15;
  const float* whh = dir ? whh_b : whh_f;
  float* hout = dir ? hb : hf;
  int tid = threadIdx.x;
  // load + split Whh slice: 128 LDS rows = 4 gate types x 32 j
  for (int i = 0; i < 128; ++i) {
    int q = i >> 5, u = i & 31;
    int gate = q * 256 + js * 32 + u;
    float v = whh[gate * 256 + tid];
    u16 hh = f2bf(v);
    wlh[i * LW + tid] = hh;
    wll[i * LW + tid] = f2bf(v - bf2f(hh));
  }
  int b_l = tid >> 4, jj = tid & 15;
  int b_g = bs * 16 + b_l;
  int jg0 = js * 32 + jj * 2;
  float cv0, cv1;
  if (first) {
    const float* c0 = dir ? c0b : c0f;
    cv0 = c0[b_g * 256 + jg0];
    cv1 = c0[b_g * 256 + jg0 + 1];
  } else {
    cv0 = cstate[(dir * 256 + b_g) * 256 + jg0];
    cv1 = cstate[(dir * 256 + b_g) * 256 + jg0 + 1];
  }
  int w = tid >> 6, l = tid & 63, la = l & 15, lk = (l >> 4) * 8;
  const float* h0 = dir ? h0b : h0f;
  __syncthreads();
  for (int sl = 0; sl < S; ++sl) {
    int sg = s0 + sl;
    int t_io = dir ? 127 - sg : sg;
    const float* hsrc; long abase;
    if (sg == 0) { hsrc = h0; abase = (long)(bs * 16 + la) * 256; }
    else { int tp = dir ? t_io + 1 : t_io - 1; hsrc = hout; abase = ((long)(bs * 16 + la) * 128 + tp) * 256; }
    f32x4 a0 = (f32x4){0.f,0.f,0.f,0.f}, a1 = (f32x4){0.f,0.f,0.f,0.f};
#pragma unroll
    for (int ks = 0; ks < 8; ++ks) {
      int k = ks * 32 + lk;
      f32x4 v0 = *(const f32x4*)(hsrc + abase + k);
      f32x4 v1 = *(const f32x4*)(hsrc + abase + k + 4);
      bf16x8 ah, al;
      split8(v0, v1, ah, al);
      {
        int row = w * 32 + la;
        bf16x8 bh = *(const bf16x8*)(wlh + row * LW + k);
        bf16x8 bl = *(const bf16x8*)(wll + row * LW + k);
        a0 = __builtin_amdgcn_mfma_f32_16x16x32_bf16(ah, bh, a0, 0, 0, 0);
        a0 = __builtin_amdgcn_mfma_f32_16x16x32_bf16(ah, bl, a0, 0, 0, 0);
        a0 = __builtin_amdgcn_mfma_f32_16x16x32_bf16(al, bh, a0, 0, 0, 0);
      }
      {
        int row = w * 32 + 16 + la;
        bf16x8 bh = *(const bf16x8*)(wlh + row * LW + k);
        bf16x8 bl = *(const bf16x8*)(wll + row * LW + k);
        a1 = __builtin_amdgcn_mfma_f32_16x16x32_bf16(ah, bh, a1, 0, 0, 0);
        a1 = __builtin_amdgcn_mfma_f32_16x16x32_bf16(ah, bl, a1, 0, 0, 0);
        a1 = __builtin_amdgcn_mfma_f32_16x16x32_bf16(al, bh, a1, 0, 0, 0);
      }
    }
#pragma unroll
    for (int r = 0; r < 4; ++r) {
      gl[((l >> 4) * 4 + r) * 132 + w * 32 + la] = a0[r];
      gl[((l >> 4) * 4 + r) * 132 + w * 32 + 16 + la] = a1[r];
    }
    __syncthreads();
    long xrow = ((long)(dir * 256 + b_g) * S + sl) * 1024;
    float hv0, hv1;
    {
      int jl = jj * 2, jg = js * 32 + jl;
      float gi = gl[b_l * 132 + jl]      + xw[xrow + jg];
      float gf = gl[b_l * 132 + 32 + jl] + xw[xrow + 256 + jg];
      float gg = gl[b_l * 132 + 64 + jl] + xw[xrow + 512 + jg];
      float go = gl[b_l * 132 + 96 + jl] + xw[xrow + 768 + jg];
      float c = sigm(gf) * cv0 + sigm(gi) * tanhf_(gg);
      cv0 = c; hv0 = sigm(go) * tanhf_(c);
    }
    {
      int jl = jj * 2 + 1, jg = js * 32 + jl;
      float gi = gl[b_l * 132 + jl]      + xw[xrow + jg];
      float gf = gl[b_l * 132 + 32 + jl] + xw[xrow + 256 + jg];
      float gg = gl[b_l * 132 + 64 + jl] + xw[xrow + 512 + jg];
      float go = gl[b_l * 132 + 96 + jl] + xw[xrow + 768 + jg];
      float c = sigm(gf) * cv1 + sigm(gi) * tanhf_(gg);
      cv1 = c; hv1 = sigm(go) * tanhf_(c);
    }
    *(float2*)(hout + ((long)b_g * 128 + t_io) * 256 + jg0) = make_float2(hv0, hv1);
    __syncthreads();
    if (tid == 0) {
      __threadfence();
      __hip_atomic_fetch_add(&flags[sl * 32 + G], 1u, __ATOMIC_RELEASE, __HIP_MEMORY_SCOPE_AGENT);
      int guard = 0;
      while (__hip_atomic_load(&flags[sl * 32 + G], __ATOMIC_ACQUIRE, __HIP_MEMORY_SCOPE_AGENT) < 8u
             && ++guard < (1 << 26)) {}
      __threadfence();
    }
    __syncthreads();
  }
  if (!last) {
    cstate[(dir * 256 + b_g) * 256 + jg0] = cv0;
    cstate[(dir * 256 + b_g) * 256 + jg0 + 1] = cv1;
  }
}

// ---------- K3: emission  emis[m][16] = [hf|hb] @ W_emit^T + b_emit ----------
__global__ __launch_bounds__(256) void k_emis(const float* __restrict__ hf, const float* __restrict__ hb,
    const u16* __restrict__ weh, const u16* __restrict__ wel,
    const float* __restrict__ bemit, float* __restrict__ emis) {
  int w = threadIdx.x >> 6, l = threadIdx.x & 63;
  int la = l & 15, lk = (l >> 4) * 8;
  long m0 = (long)blockIdx.x * 64 + w * 16;
  long am = m0 + la;
  f32x4 acc = (f32x4){0.f, 0.f, 0.f, 0.f};
#pragma unroll
  for (int ks = 0; ks < 16; ++ks) {
    int k = ks * 32 + lk;
    const float* src = (k < 256) ? (hf + am * 256 + k) : (hb + am * 256 + (k - 256));
    f32x4 v0 = *(const f32x4*)src;
    f32x4 v1 = *(const f32x4*)(src + 4);
    bf16x8 ah, al;
    split8(v0, v1, ah, al);
    bf16x8 bh = *(const bf16x8*)(weh + la * 512 + k);
    bf16x8 bl = *(const bf16x8*)(wel + la * 512 + k);
    acc = __builtin_amdgcn_mfma_f32_16x16x32_bf16(ah, bh, acc, 0, 0, 0);
    acc = __builtin_amdgcn_mfma_f32_16x16x32_bf16(ah, bl, acc, 0, 0, 0);
    acc = __builtin_amdgcn_mfma_f32_16x16x32_bf16(al, bh, acc, 0, 0, 0);
  }
  int kout = la;
  float bias = (kout < 9) ? bemit[kout] : 0.f;
  long mr = m0 + (l >> 4) * 4;
#pragma unroll
  for (int r = 0; r < 4; ++r)
    emis[(mr + r) * 16 + kout] = acc[r] + bias;
}

// ---------- K4: CRF forward (logZ) + gold-path numerator ----------
__global__ __launch_bounds__(256) void k_crf(const float* __restrict__ emis, const int* __restrict__ ixin,
    const int* __restrict__ label, const float* __restrict__ startt, const float* __restrict__ endt,
    const float* __restrict__ trans, float* __restrict__ lossp) {
  __shared__ float al_s[16][16];
  __shared__ float tr_s[9][16];
  __shared__ float num_s[16];
  __shared__ float red_s[16];
  int tid = threadIdx.x, bl = tid >> 4, k = tid & 15;
  int b = blockIdx.x * 16 + bl;
  if (bl < 9) tr_s[bl][k] = (k < 9) ? trans[bl * 9 + k] : 0.f;
  float a = 0.f, num = 0.f;
  int lastlab = 0;
  if (k < 9) a = startt[k] + emis[((long)b * 128) * 16 + k];
  al_s[bl][k] = a;
  if (k == 9) {
    int l0 = label[b * 128];
    num = startt[l0] + emis[((long)b * 128) * 16 + l0];
    lastlab = l0;
  }
  __syncthreads();
  for (int t = 1; t < 128; ++t) {
    bool msk = ixin[b * 128 + t] != 0;
    float anew = a;
    if (k < 9) {
      float mx = -1e30f;
#pragma unroll
      for (int j = 0; j < 9; ++j) mx = fmaxf(mx, al_s[bl][j] + tr_s[j][k]);
      float ss = 0.f;
#pragma unroll
      for (int j = 0; j < 9; ++j) ss += __expf(al_s[bl][j] + tr_s[j][k] - mx);
      anew = mx + __logf(ss) + emis[((long)b * 128 + t) * 16 + k];
      if (!msk) anew = a;
    } else if (k == 9 && msk) {
      int lt = label[b * 128 + t];
      num += tr_s[lastlab][lt] + emis[((long)b * 128 + t) * 16 + lt];
      lastlab = lt;
    }
    __syncthreads();
    if (k < 9) { a = anew; al_s[bl][k] = a; }
    __syncthreads();
  }
  if (k == 9) num_s[bl] = num + endt[lastlab];
  __syncthreads();
  if (k == 0) {
    float mx = -1e30f;
#pragma unroll
    for (int j = 0; j < 9; ++j) mx = fmaxf(mx, al_s[bl][j] + endt[j]);
    float ss = 0.f;
#pragma unroll
    for (int j = 0; j < 9; ++j) ss += __expf(al_s[bl][j] + endt[j] - mx);
    red_s[bl] = (mx + __logf(ss)) - num_s[bl];
  }
  __syncthreads();
  if (tid == 0) {
    float s = 0.f;
    for (int i = 0; i < 16; ++i) s += red_s[i];
    lossp[blockIdx.x] = s;
  }
}

// ---------- K5: Viterbi forward storing backpointers ----------
__global__ __launch_bounds__(256) void k_vit(const float* __restrict__ emis,
    const float* __restrict__ startt, const float* __restrict__ trans,
    unsigned char* __restrict__ bp, float* __restrict__ vfin) {
  __shared__ float al_s[16][16];
  __shared__ float tr_s[9][16];
  int tid = threadIdx.x, bl = tid >> 4, k = tid & 15;
  int b = blockIdx.x * 16 + bl;
  if (bl < 9) tr_s[bl][k] = (k < 9) ? trans[bl * 9 + k] : 0.f;
  float v = -1e30f;
  if (k < 9) v = startt[k] + emis[((long)b * 128) * 16 + k];
  al_s[bl][k] = v;
  __syncthreads();
  for (int t = 1; t < 128; ++t) {
    float vnew = v;
    if (k < 9) {
      float best = -1e30f; int bi = 0;
#pragma unroll
      for (int j = 0; j < 9; ++j) {
        float tot = al_s[bl][j] + tr_s[j][k];
        if (tot > best) { best = tot; bi = j; }
      }
      vnew = best + emis[((long)b * 128 + t) * 16 + k];
      bp[((long)b * 127 + (t - 1)) * 16 + k] = (unsigned char)bi;
    }
    __syncthreads();
    if (k < 9) { v = vnew; al_s[bl][k] = v; }
    __syncthreads();
  }
  vfin[b * 16 + k] = (k < 9) ? v : -1e30f;
}

// ---------- K6: backtrace (LDS-staged) + loss reduction ----------
__global__ __launch_bounds__(256) void k_fin(const float* __restrict__ vfin, const float* __restrict__ endt,
    const unsigned char* __restrict__ bp, const float* __restrict__ lossp, float* __restrict__ out) {
  __shared__ unsigned char bpl[16 * 127 * 16];  // 32512 B
  int tid = threadIdx.x;
  const unsigned* src = (const unsigned*)(bp + (long)blockIdx.x * 32512);
  unsigned* dst = (unsigned*)bpl;
  for (int i = tid; i < 8128; i += 256) dst[i] = src[i];
  __syncthreads();
  if (tid < 16) {
    int b = blockIdx.x * 16 + tid;
    float best = -1e30f; int tag = 0;
#pragma unroll
    for (int j = 0; j < 9; ++j) {
      float v = vfin[b * 16 + j] + endt[j];
      if (v > best) { best = v; tag = j; }
    }
    out[1 + b * 128 + 127] = (float)tag;
    for (int t = 127; t >= 1; --t) {
      tag = bpl[(tid * 127 + (t - 1)) * 16 + tag];
      out[1 + b * 128 + t - 1] = (float)tag;
    }
  }
  if (blockIdx.x == 0 && tid == 0) {
    float s = 0.f;
    for (int i = 0; i < 16; ++i) s += lossp[i];
    out[0] = s;
  }
}

__global__ void k_sent(float* out) { out[0] = -1.0e6f; }

// ---------- launch ----------
extern "C" void kernel_launch(void* const* d_in, const int* in_sizes, int n_in,
                              void* d_out, int out_size, void* d_ws, size_t ws_size,
                              hipStream_t stream) {
  const int* in_x    = (const int*)d_in[0];
  const int* label   = (const int*)d_in[1];
  const float* emb   = (const float*)d_in[2];
  const float* Wih_f = (const float*)d_in[3];
  const float* Whh_f = (const float*)d_in[4];
  const float* b_f   = (const float*)d_in[5];
  const float* Wih_b = (const float*)d_in[6];
  const float* Whh_b = (const float*)d_in[7];
  const float* b_b   = (const float*)d_in[8];
  const float* W_emit= (const float*)d_in[9];
  const float* b_emit= (const float*)d_in[10];
  const float* start_t=(const float*)d_in[11];
  const float* end_t = (const float*)d_in[12];
  const float* trans = (const float*)d_in[13];
  const float* h0f   = (const float*)d_in[14];
  const float* c0f   = (const float*)d_in[15];
  const float* h0b   = (const float*)d_in[16];
  const float* c0b   = (const float*)d_in[17];
  (void)in_sizes; (void)n_in; (void)out_size;

  auto align = [](size_t x) { return (x + 255) & ~(size_t)255; };
  size_t fixed = 0;
  fixed += align(32768L * 256 * 4);   // HF
  fixed += align(32768L * 256 * 4);   // HB
  fixed += align(2048L * 256 * 2);    // WIHH
  fixed += align(2048L * 256 * 2);    // WIHL
  fixed += align(16L * 512 * 2);      // WEH
  fixed += align(16L * 512 * 2);      // WEL
  fixed += align(32768L * 16 * 4);    // EMIS
  fixed += align(256L * 127 * 16);    // BP
  fixed += align(256L * 16 * 4);      // VFIN
  fixed += align(64 * 4);             // LOSSP
  fixed += align(128L * 32 * 4);      // FLAGS
  fixed += align(2L * 256 * 256 * 4); // CSTATE

  int S = 0;
  const int cands[4] = {128, 64, 32, 16};
  for (int ci = 0; ci < 4; ++ci) {
    size_t xb = align(2097152L * cands[ci]);
    if (xb + fixed <= ws_size) { S = cands[ci]; break; }
  }
  if (S == 0) { k_sent<<<1, 1, 0, stream>>>((float*)d_out); return; }
  int logS = __builtin_ctz(S);
  int NC = 128 / S;

  char* ws = (char*)d_ws;
  size_t o = 0;
  auto alloc = [&](size_t sz) { size_t r = o; o += (sz + 255) & ~(size_t)255; return r; };
  float* xw   = (float*)(ws + alloc(2097152L * S));
  float* hf   = (float*)(ws + alloc(32768L * 256 * 4));
  float* hb   = (float*)(ws + alloc(32768L * 256 * 4));
  u16* wihh   = (u16*)(ws + alloc(2048L * 256 * 2));
  u16* wihl   = (u16*)(ws + alloc(2048L * 256 * 2));
  u16* weh    = (u16*)(ws + alloc(16L * 512 * 2));
  u16* wel    = (u16*)(ws + alloc(16L * 512 * 2));
  float* emis = (float*)(ws + alloc(32768L * 16 * 4));
  unsigned char* bp = (unsigned char*)(ws + alloc(256L * 127 * 16));
  float* vfin = (float*)(ws + alloc(256L * 16 * 4));
  float* lossp= (float*)(ws + alloc(64 * 4));
  unsigned* flags = (unsigned*)(ws + alloc(128L * 32 * 4));
  float* cstate = (float*)(ws + alloc(2L * 256 * 256 * 4));

  k_prep_w<<<2080, 256, 0, stream>>>(Wih_f, Wih_b, W_emit, wihh, wihl, weh, wel);
  for (int c = 0; c < NC; ++c) {
    k_gemm_in<<<dim3(4 * S, 8, 2), 256, 0, stream>>>(in_x, emb, wihh, wihl, b_f, b_b,
                                                     xw, c * S, S, logS);
    hipMemsetAsync(flags, 0, (size_t)S * 32 * 4, stream);
    k_lstm<<<256, 256, 0, stream>>>(Whh_f, Whh_b, h0f, c0f, h0b, c0b, xw, hf, hb,
                                    cstate, flags, c * S, S, c == 0 ? 1 : 0, c == NC - 1 ? 1 : 0);
  }
  k_emis<<<512, 256, 0, stream>>>(hf, hb, weh, wel, b_emit, emis);
  k_crf<<<16, 256, 0, stream>>>(emis, in_x, label, start_t, end_t, trans, lossp);
  k_vit<<<16, 256, 0, stream>>>(emis, start_t, trans, bp, vfin);
  k_fin<<<16, 256, 0, stream>>>(vfin, end_t, bp, lossp, (float*)d_out);
}

// Round 3
// 2316.574 us; speedup vs baseline: 1.3212x; 1.3212x over previous
//
#include <hip/hip_runtime.h>

typedef __attribute__((ext_vector_type(8))) short bf16x8;
typedef __attribute__((ext_vector_type(4))) float f32x4;
typedef unsigned short u16;

// ---------- helpers ----------
__device__ __forceinline__ u16 f2bf(float f) {
  union { float f; unsigned u; } v; v.f = f;
  unsigned r = v.u + 0x7fffu + ((v.u >> 16) & 1u);
  return (u16)(r >> 16);
}
__device__ __forceinline__ float bf2f(u16 h) {
  union { unsigned u; float f; } v; v.u = ((unsigned)h) << 16;
  return v.f;
}
__device__ __forceinline__ void split8(const float* f8, bf16x8 &hi, bf16x8 &lo) {
#pragma unroll
  for (int e = 0; e < 8; ++e) {
    u16 h0 = f2bf(f8[e]);
    hi[e] = (short)h0;
    lo[e] = (short)f2bf(f8[e] - bf2f(h0));
  }
}
__device__ __forceinline__ void split8v(const f32x4 v0, const f32x4 v1, bf16x8 &hi, bf16x8 &lo) {
  float f8[8];
#pragma unroll
  for (int e = 0; e < 4; ++e) { f8[e] = v0[e]; f8[4 + e] = v1[e]; }
  split8(f8, hi, lo);
}
__device__ __forceinline__ float sigm(float x) { return 1.f / (1.f + __expf(-x)); }
__device__ __forceinline__ float tanhf_(float x) { return 1.f - 2.f / (__expf(2.f * x) + 1.f); }

// agent-scope fine-grained coherent 8B ops (no L2 writeback/invalidate)
__device__ __forceinline__ unsigned long long ld_agent_u64(const float* p) {
  return __hip_atomic_load((const unsigned long long*)p, __ATOMIC_RELAXED, __HIP_MEMORY_SCOPE_AGENT);
}
__device__ __forceinline__ void st_agent_u64(float* p, float a, float b) {
  union { float f[2]; unsigned long long u; } v;
  v.f[0] = a; v.f[1] = b;
  __hip_atomic_store((unsigned long long*)p, v.u, __ATOMIC_RELAXED, __HIP_MEMORY_SCOPE_AGENT);
}

// ---------- K0: Wih (f|b concat [2048][256]) and W_emit ([16][512], rows>=9 zero) -> bf16 hi/lo ----------
__global__ __launch_bounds__(256) void k_prep_w(const float* __restrict__ wf, const float* __restrict__ wb,
                                                const float* __restrict__ we,
                                                u16* __restrict__ wihh, u16* __restrict__ wihl,
                                                u16* __restrict__ weh, u16* __restrict__ wel) {
  int i = blockIdx.x * 256 + threadIdx.x;
  float v; u16 *dh, *dl; int o;
  if (i < 524288) {
    int g = i >> 8, k = i & 255;
    v = (g < 1024) ? wf[g * 256 + k] : wb[(g - 1024) * 256 + k];
    dh = wihh; dl = wihl; o = i;
  } else {
    int j = i - 524288;
    int r = j >> 9, k = j & 511;
    v = (r < 9) ? we[r * 512 + k] : 0.f;
    dh = weh; dl = wel; o = j;
  }
  u16 hh = f2bf(v);
  dh[o] = hh; dl[o] = f2bf(v - bf2f(hh));
}

// ---------- K1: chunked input GEMM ----------
__global__ __launch_bounds__(256) void k_gemm_in(const int* __restrict__ ix,
    const float* __restrict__ emb,
    const u16* __restrict__ wh, const u16* __restrict__ wl,
    const float* __restrict__ bf_, const float* __restrict__ bb_,
    float* __restrict__ xw, int c0step, int S, int logS) {
  int w = threadIdx.x >> 6, l = threadIdx.x & 63;
  int la = l & 15, lk = (l >> 4) * 8;
  int dir = blockIdx.z;
  int m0 = blockIdx.x * 64 + w * 16;
  int n0 = blockIdx.y * 128;
  int mA = m0 + la;
  int bA = mA >> logS, slA = mA & (S - 1);
  int sg = c0step + slA;
  int tA = dir ? (127 - sg) : sg;
  const float* erow = emb + (long)ix[bA * 128 + tA] * 256;
  f32x4 acc[8];
#pragma unroll
  for (int i = 0; i < 8; ++i) acc[i] = (f32x4){0.f, 0.f, 0.f, 0.f};
#pragma unroll
  for (int ks = 0; ks < 8; ++ks) {
    int k = ks * 32 + lk;
    f32x4 v0 = *(const f32x4*)(erow + k);
    f32x4 v1 = *(const f32x4*)(erow + k + 4);
    bf16x8 ah, al;
    split8v(v0, v1, ah, al);
#pragma unroll
    for (int nt = 0; nt < 8; ++nt) {
      int g = n0 + nt * 16 + la;
      long go = (long)(dir * 1024 + g) * 256 + k;
      bf16x8 bh = *(const bf16x8*)(wh + go);
      bf16x8 bl = *(const bf16x8*)(wl + go);
      acc[nt] = __builtin_amdgcn_mfma_f32_16x16x32_bf16(ah, bh, acc[nt], 0, 0, 0);
      acc[nt] = __builtin_amdgcn_mfma_f32_16x16x32_bf16(ah, bl, acc[nt], 0, 0, 0);
      acc[nt] = __builtin_amdgcn_mfma_f32_16x16x32_bf16(al, bh, acc[nt], 0, 0, 0);
    }
  }
  int mrb = m0 + (l >> 4) * 4;
#pragma unroll
  for (int nt = 0; nt < 8; ++nt) {
    int g = n0 + nt * 16 + la;
    float bias = (dir ? bb_ : bf_)[g];
#pragma unroll
    for (int r = 0; r < 4; ++r) {
      int m2 = mrb + r;
      int b2 = m2 >> logS, sl2 = m2 & (S - 1);
      xw[((long)(dir * 256 + b2) * S + sl2) * 1024 + g] = acc[nt][r] + bias;
    }
  }
}

// ---------- K2: BiLSTM recurrence (chunk of S steps) ----------
// 256 blocks = 2 dir x 16 batch-slices x 8 j-slices; Whh slice (hi+lo bf16) resident in LDS.
// Cross-block h exchange via agent-scope fine-grained atomics (no L2 flush/inv).
#define LW 264
__global__ __launch_bounds__(256) void k_lstm(
    const float* __restrict__ whh_f, const float* __restrict__ whh_b,
    const float* __restrict__ h0f, const float* __restrict__ c0f,
    const float* __restrict__ h0b, const float* __restrict__ c0b,
    const float* __restrict__ xw,
    float* __restrict__ hf, float* __restrict__ hb,
    float* __restrict__ cstate, unsigned* __restrict__ flags,
    int s0, int S, int first, int last) {
  __shared__ u16 wlh[128 * LW];
  __shared__ u16 wll[128 * LW];
  __shared__ float gl[16 * 132];
  int bid = blockIdx.x;
  int js = (bid >> 3) & 7;
  int G = ((bid >> 6) << 3) | (bid & 7);   // group id; members share blockIdx%8 (same-XCD heuristic)
  int dir = G >> 4, bs = G & 15;
  const float* whh = dir ? whh_b : whh_f;
  float* hout = dir ? hb : hf;
  int tid = threadIdx.x;
  for (int i = 0; i < 128; ++i) {
    int q = i >> 5, u = i & 31;
    int gate = q * 256 + js * 32 + u;
    float v = whh[gate * 256 + tid];
    u16 hh = f2bf(v);
    wlh[i * LW + tid] = hh;
    wll[i * LW + tid] = f2bf(v - bf2f(hh));
  }
  int b_l = tid >> 4, jj = tid & 15;
  int b_g = bs * 16 + b_l;
  int jg0 = js * 32 + jj * 2;
  float cv0, cv1;
  if (first) {
    const float* c0 = dir ? c0b : c0f;
    cv0 = c0[b_g * 256 + jg0];
    cv1 = c0[b_g * 256 + jg0 + 1];
  } else {
    cv0 = cstate[(dir * 256 + b_g) * 256 + jg0];
    cv1 = cstate[(dir * 256 + b_g) * 256 + jg0 + 1];
  }
  int w = tid >> 6, l = tid & 63, la = l & 15;
  const float* h0 = dir ? h0b : h0f;
  __syncthreads();
  for (int sl = 0; sl < S; ++sl) {
    int sg = s0 + sl;
    int t_io = dir ? 127 - sg : sg;
    // ---- xw prefetch for this step (barrier-independent, issue first) ----
    long xrow = ((long)(dir * 256 + b_g) * S + sl) * 1024 + jg0;
    float2 xi = *(const float2*)(xw + xrow);
    float2 xf = *(const float2*)(xw + xrow + 256);
    float2 xg = *(const float2*)(xw + xrow + 512);
    float2 xo = *(const float2*)(xw + xrow + 768);
    // ---- stage all h loads (agent-coherent) into registers before any MFMA ----
    const float* hsrc; long abase;
    if (sg == 0) { hsrc = h0; abase = (long)(bs * 16 + la) * 256; }
    else { int tp = dir ? t_io + 1 : t_io - 1; hsrc = hout; abase = ((long)(bs * 16 + la) * 128 + tp) * 256; }
    unsigned long long hq[32];
#pragma unroll
    for (int i = 0; i < 32; ++i) hq[i] = ld_agent_u64(hsrc + abase + i * 2);
    f32x4 a0 = (f32x4){0.f,0.f,0.f,0.f}, a1 = (f32x4){0.f,0.f,0.f,0.f};
    int lk = (l >> 4) * 8;
#pragma unroll
    for (int ks = 0; ks < 8; ++ks) {
      int k = ks * 32 + lk;
      union { unsigned long long u[4]; float f[8]; } hv;
#pragma unroll
      for (int q = 0; q < 4; ++q) hv.u[q] = hq[(k >> 1) - ((ks * 32) >> 1) + (ks * 16) + q];
      bf16x8 ah, al;
      split8(hv.f, ah, al);
      {
        int row = w * 32 + la;
        bf16x8 bh = *(const bf16x8*)(wlh + row * LW + k);
        bf16x8 bl = *(const bf16x8*)(wll + row * LW + k);
        a0 = __builtin_amdgcn_mfma_f32_16x16x32_bf16(ah, bh, a0, 0, 0, 0);
        a0 = __builtin_amdgcn_mfma_f32_16x16x32_bf16(ah, bl, a0, 0, 0, 0);
        a0 = __builtin_amdgcn_mfma_f32_16x16x32_bf16(al, bh, a0, 0, 0, 0);
      }
      {
        int row = w * 32 + 16 + la;
        bf16x8 bh = *(const bf16x8*)(wlh + row * LW + k);
        bf16x8 bl = *(const bf16x8*)(wll + row * LW + k);
        a1 = __builtin_amdgcn_mfma_f32_16x16x32_bf16(ah, bh, a1, 0, 0, 0);
        a1 = __builtin_amdgcn_mfma_f32_16x16x32_bf16(ah, bl, a1, 0, 0, 0);
        a1 = __builtin_amdgcn_mfma_f32_16x16x32_bf16(al, bh, a1, 0, 0, 0);
      }
    }
#pragma unroll
    for (int r = 0; r < 4; ++r) {
      gl[((l >> 4) * 4 + r) * 132 + w * 32 + la] = a0[r];
      gl[((l >> 4) * 4 + r) * 132 + w * 32 + 16 + la] = a1[r];
    }
    __syncthreads();
    float hv0, hv1;
    {
      int jl = jj * 2;
      float gi = gl[b_l * 132 + jl]      + xi.x;
      float gf = gl[b_l * 132 + 32 + jl] + xf.x;
      float gg = gl[b_l * 132 + 64 + jl] + xg.x;
      float go = gl[b_l * 132 + 96 + jl] + xo.x;
      float c = sigm(gf) * cv0 + sigm(gi) * tanhf_(gg);
      cv0 = c; hv0 = sigm(go) * tanhf_(c);
    }
    {
      int jl = jj * 2 + 1;
      float gi = gl[b_l * 132 + jl]      + xi.y;
      float gf = gl[b_l * 132 + 32 + jl] + xf.y;
      float gg = gl[b_l * 132 + 64 + jl] + xg.y;
      float go = gl[b_l * 132 + 96 + jl] + xo.y;
      float c = sigm(gf) * cv1 + sigm(gi) * tanhf_(gg);
      cv1 = c; hv1 = sigm(go) * tanhf_(c);
    }
    // agent-coherent h store (write-through; no fence needed)
    st_agent_u64(hout + ((long)b_g * 128 + t_io) * 256 + jg0, hv0, hv1);
    asm volatile("s_waitcnt vmcnt(0)" ::: "memory");  // per-wave drain before signaling
    __syncthreads();
    if (tid == 0) {
      unsigned* fl = &flags[(sg * 32 + G) * 32];
      __hip_atomic_fetch_add(fl, 1u, __ATOMIC_RELAXED, __HIP_MEMORY_SCOPE_AGENT);
      int guard = 0;
      while (__hip_atomic_load(fl, __ATOMIC_RELAXED, __HIP_MEMORY_SCOPE_AGENT) < 8u
             && ++guard < (1 << 26)) {}
    }
    __syncthreads();
  }
  if (!last) {
    cstate[(dir * 256 + b_g) * 256 + jg0] = cv0;
    cstate[(dir * 256 + b_g) * 256 + jg0 + 1] = cv1;
  }
}

// ---------- K3: emission  emis[m][16] = [hf|hb] @ W_emit^T + b_emit ----------
__global__ __launch_bounds__(256) void k_emis(const float* __restrict__ hf, const float* __restrict__ hb,
    const u16* __restrict__ weh, const u16* __restrict__ wel,
    const float* __restrict__ bemit, float* __restrict__ emis) {
  int w = threadIdx.x >> 6, l = threadIdx.x & 63;
  int la = l & 15, lk = (l >> 4) * 8;
  long m0 = (long)blockIdx.x * 64 + w * 16;
  long am = m0 + la;
  f32x4 acc = (f32x4){0.f, 0.f, 0.f, 0.f};
#pragma unroll
  for (int ks = 0; ks < 16; ++ks) {
    int k = ks * 32 + lk;
    const float* src = (k < 256) ? (hf + am * 256 + k) : (hb + am * 256 + (k - 256));
    f32x4 v0 = *(const f32x4*)src;
    f32x4 v1 = *(const f32x4*)(src + 4);
    bf16x8 ah, al;
    split8v(v0, v1, ah, al);
    bf16x8 bh = *(const bf16x8*)(weh + la * 512 + k);
    bf16x8 bl = *(const bf16x8*)(wel + la * 512 + k);
    acc = __builtin_amdgcn_mfma_f32_16x16x32_bf16(ah, bh, acc, 0, 0, 0);
    acc = __builtin_amdgcn_mfma_f32_16x16x32_bf16(ah, bl, acc, 0, 0, 0);
    acc = __builtin_amdgcn_mfma_f32_16x16x32_bf16(al, bh, acc, 0, 0, 0);
  }
  int kout = la;
  float bias = (kout < 9) ? bemit[kout] : 0.f;
  long mr = m0 + (l >> 4) * 4;
#pragma unroll
  for (int r = 0; r < 4; ++r)
    emis[(mr + r) * 16 + kout] = acc[r] + bias;
}

// ---------- K4: CRF forward (logZ) + gold-path numerator ----------
__global__ __launch_bounds__(256) void k_crf(const float* __restrict__ emis, const int* __restrict__ ixin,
    const int* __restrict__ label, const float* __restrict__ startt, const float* __restrict__ endt,
    const float* __restrict__ trans, float* __restrict__ lossp) {
  __shared__ float al_s[16][16];
  __shared__ float tr_s[9][16];
  __shared__ float num_s[16];
  __shared__ float red_s[16];
  int tid = threadIdx.x, bl = tid >> 4, k = tid & 15;
  int b = blockIdx.x * 16 + bl;
  if (bl < 9) tr_s[bl][k] = (k < 9) ? trans[bl * 9 + k] : 0.f;
  float a = 0.f, num = 0.f;
  int lastlab = 0;
  if (k < 9) a = startt[k] + emis[((long)b * 128) * 16 + k];
  al_s[bl][k] = a;
  if (k == 9) {
    int l0 = label[b * 128];
    num = startt[l0] + emis[((long)b * 128) * 16 + l0];
    lastlab = l0;
  }
  __syncthreads();
  for (int t = 1; t < 128; ++t) {
    bool msk = ixin[b * 128 + t] != 0;
    float anew = a;
    if (k < 9) {
      float mx = -1e30f;
#pragma unroll
      for (int j = 0; j < 9; ++j) mx = fmaxf(mx, al_s[bl][j] + tr_s[j][k]);
      float ss = 0.f;
#pragma unroll
      for (int j = 0; j < 9; ++j) ss += __expf(al_s[bl][j] + tr_s[j][k] - mx);
      anew = mx + __logf(ss) + emis[((long)b * 128 + t) * 16 + k];
      if (!msk) anew = a;
    } else if (k == 9 && msk) {
      int lt = label[b * 128 + t];
      num += tr_s[lastlab][lt] + emis[((long)b * 128 + t) * 16 + lt];
      lastlab = lt;
    }
    __syncthreads();
    if (k < 9) { a = anew; al_s[bl][k] = a; }
    __syncthreads();
  }
  if (k == 9) num_s[bl] = num + endt[lastlab];
  __syncthreads();
  if (k == 0) {
    float mx = -1e30f;
#pragma unroll
    for (int j = 0; j < 9; ++j) mx = fmaxf(mx, al_s[bl][j] + endt[j]);
    float ss = 0.f;
#pragma unroll
    for (int j = 0; j < 9; ++j) ss += __expf(al_s[bl][j] + endt[j] - mx);
    red_s[bl] = (mx + __logf(ss)) - num_s[bl];
  }
  __syncthreads();
  if (tid == 0) {
    float s = 0.f;
    for (int i = 0; i < 16; ++i) s += red_s[i];
    lossp[blockIdx.x] = s;
  }
}

// ---------- K5: Viterbi forward storing backpointers ----------
__global__ __launch_bounds__(256) void k_vit(const float* __restrict__ emis,
    const float* __restrict__ startt, const float* __restrict__ trans,
    unsigned char* __restrict__ bp, float* __restrict__ vfin) {
  __shared__ float al_s[16][16];
  __shared__ float tr_s[9][16];
  int tid = threadIdx.x, bl = tid >> 4, k = tid & 15;
  int b = blockIdx.x * 16 + bl;
  if (bl < 9) tr_s[bl][k] = (k < 9) ? trans[bl * 9 + k] : 0.f;
  float v = -1e30f;
  if (k < 9) v = startt[k] + emis[((long)b * 128) * 16 + k];
  al_s[bl][k] = v;
  __syncthreads();
  for (int t = 1; t < 128; ++t) {
    float vnew = v;
    if (k < 9) {
      float best = -1e30f; int bi = 0;
#pragma unroll
      for (int j = 0; j < 9; ++j) {
        float tot = al_s[bl][j] + tr_s[j][k];
        if (tot > best) { best = tot; bi = j; }
      }
      vnew = best + emis[((long)b * 128 + t) * 16 + k];
      bp[((long)b * 127 + (t - 1)) * 16 + k] = (unsigned char)bi;
    }
    __syncthreads();
    if (k < 9) { v = vnew; al_s[bl][k] = v; }
    __syncthreads();
  }
  vfin[b * 16 + k] = (k < 9) ? v : -1e30f;
}

// ---------- K6: backtrace (LDS-staged) + loss reduction ----------
__global__ __launch_bounds__(256) void k_fin(const float* __restrict__ vfin, const float* __restrict__ endt,
    const unsigned char* __restrict__ bp, const float* __restrict__ lossp, float* __restrict__ out) {
  __shared__ unsigned char bpl[16 * 127 * 16];
  int tid = threadIdx.x;
  const unsigned* src = (const unsigned*)(bp + (long)blockIdx.x * 32512);
  unsigned* dst = (unsigned*)bpl;
  for (int i = tid; i < 8128; i += 256) dst[i] = src[i];
  __syncthreads();
  if (tid < 16) {
    int b = blockIdx.x * 16 + tid;
    float best = -1e30f; int tag = 0;
#pragma unroll
    for (int j = 0; j < 9; ++j) {
      float v = vfin[b * 16 + j] + endt[j];
      if (v > best) { best = v; tag = j; }
    }
    out[1 + b * 128 + 127] = (float)tag;
    for (int t = 127; t >= 1; --t) {
      tag = bpl[(tid * 127 + (t - 1)) * 16 + tag];
      out[1 + b * 128 + t - 1] = (float)tag;
    }
  }
  if (blockIdx.x == 0 && tid == 0) {
    float s = 0.f;
    for (int i = 0; i < 16; ++i) s += lossp[i];
    out[0] = s;
  }
}

__global__ void k_sent(float* out) { out[0] = -1.0e6f; }

// ---------- launch ----------
extern "C" void kernel_launch(void* const* d_in, const int* in_sizes, int n_in,
                              void* d_out, int out_size, void* d_ws, size_t ws_size,
                              hipStream_t stream) {
  const int* in_x    = (const int*)d_in[0];
  const int* label   = (const int*)d_in[1];
  const float* emb   = (const float*)d_in[2];
  const float* Wih_f = (const float*)d_in[3];
  const float* Whh_f = (const float*)d_in[4];
  const float* b_f   = (const float*)d_in[5];
  const float* Wih_b = (const float*)d_in[6];
  const float* Whh_b = (const float*)d_in[7];
  const float* b_b   = (const float*)d_in[8];
  const float* W_emit= (const float*)d_in[9];
  const float* b_emit= (const float*)d_in[10];
  const float* start_t=(const float*)d_in[11];
  const float* end_t = (const float*)d_in[12];
  const float* trans = (const float*)d_in[13];
  const float* h0f   = (const float*)d_in[14];
  const float* c0f   = (const float*)d_in[15];
  const float* h0b   = (const float*)d_in[16];
  const float* c0b   = (const float*)d_in[17];
  (void)in_sizes; (void)n_in; (void)out_size;

  auto align = [](size_t x) { return (x + 255) & ~(size_t)255; };
  size_t fixed = 0;
  fixed += align(32768L * 256 * 4);        // HF
  fixed += align(32768L * 256 * 4);        // HB
  fixed += align(2048L * 256 * 2);         // WIHH
  fixed += align(2048L * 256 * 2);         // WIHL
  fixed += align(16L * 512 * 2);           // WEH
  fixed += align(16L * 512 * 2);           // WEL
  fixed += align(32768L * 16 * 4);         // EMIS
  fixed += align(256L * 127 * 16);         // BP
  fixed += align(256L * 16 * 4);           // VFIN
  fixed += align(64 * 4);                  // LOSSP
  fixed += align(128L * 32 * 32 * 4);      // FLAGS (128B-padded per group/step)
  fixed += align(2L * 256 * 256 * 4);      // CSTATE

  int S = 0;
  const int cands[4] = {128, 64, 32, 16};
  for (int ci = 0; ci < 4; ++ci) {
    size_t xb = align(2097152L * cands[ci]);
    if (xb + fixed <= ws_size) { S = cands[ci]; break; }
  }
  if (S == 0) { k_sent<<<1, 1, 0, stream>>>((float*)d_out); return; }
  int logS = __builtin_ctz(S);
  int NC = 128 / S;

  char* ws = (char*)d_ws;
  size_t o = 0;
  auto alloc = [&](size_t sz) { size_t r = o; o += (sz + 255) & ~(size_t)255; return r; };
  float* xw   = (float*)(ws + alloc(2097152L * S));
  float* hf   = (float*)(ws + alloc(32768L * 256 * 4));
  float* hb   = (float*)(ws + alloc(32768L * 256 * 4));
  u16* wihh   = (u16*)(ws + alloc(2048L * 256 * 2));
  u16* wihl   = (u16*)(ws + alloc(2048L * 256 * 2));
  u16* weh    = (u16*)(ws + alloc(16L * 512 * 2));
  u16* wel    = (u16*)(ws + alloc(16L * 512 * 2));
  float* emis = (float*)(ws + alloc(32768L * 16 * 4));
  unsigned char* bp = (unsigned char*)(ws + alloc(256L * 127 * 16));
  float* vfin = (float*)(ws + alloc(256L * 16 * 4));
  float* lossp= (float*)(ws + alloc(64 * 4));
  unsigned* flags = (unsigned*)(ws + alloc(128L * 32 * 32 * 4));
  float* cstate = (float*)(ws + alloc(2L * 256 * 256 * 4));

  hipMemsetAsync(flags, 0, 128L * 32 * 32 * 4, stream);
  k_prep_w<<<2080, 256, 0, stream>>>(Wih_f, Wih_b, W_emit, wihh, wihl, weh, wel);
  for (int c = 0; c < NC; ++c) {
    k_gemm_in<<<dim3(4 * S, 8, 2), 256, 0, stream>>>(in_x, emb, wihh, wihl, b_f, b_b,
                                                     xw, c * S, S, logS);
    k_lstm<<<256, 256, 0, stream>>>(Whh_f, Whh_b, h0f, c0f, h0b, c0b, xw, hf, hb,
                                    cstate, flags, c * S, S, c == 0 ? 1 : 0, c == NC - 1 ? 1 : 0);
  }
  k_emis<<<512, 256, 0, stream>>>(hf, hb, weh, wel, b_emit, emis);
  k_crf<<<16, 256, 0, stream>>>(emis, in_x, label, start_t, end_t, trans, lossp);
  k_vit<<<16, 256, 0, stream>>>(emis, start_t, trans, bp, vfin);
  k_fin<<<16, 256, 0, stream>>>(vfin, end_t, bp, lossp, (float*)d_out);
}

// Round 4
// 1174.249 us; speedup vs baseline: 2.6065x; 1.9728x over previous
//
#include <hip/hip_runtime.h>

typedef __attribute__((ext_vector_type(8))) short bf16x8;
typedef __attribute__((ext_vector_type(4))) float f32x4;
typedef unsigned short u16;

// ---------- helpers ----------
__device__ __forceinline__ u16 f2bf(float f) {
  union { float f; unsigned u; } v; v.f = f;
  unsigned r = v.u + 0x7fffu + ((v.u >> 16) & 1u);
  return (u16)(r >> 16);
}
__device__ __forceinline__ float bf2f(u16 h) {
  union { unsigned u; float f; } v; v.u = ((unsigned)h) << 16;
  return v.f;
}
__device__ __forceinline__ void split8(const float* f8, bf16x8 &hi, bf16x8 &lo) {
#pragma unroll
  for (int e = 0; e < 8; ++e) {
    u16 h0 = f2bf(f8[e]);
    hi[e] = (short)h0;
    lo[e] = (short)f2bf(f8[e] - bf2f(h0));
  }
}
__device__ __forceinline__ void split8v(const f32x4 v0, const f32x4 v1, bf16x8 &hi, bf16x8 &lo) {
  float f8[8];
#pragma unroll
  for (int e = 0; e < 4; ++e) { f8[e] = v0[e]; f8[4 + e] = v1[e]; }
  split8(f8, hi, lo);
}
__device__ __forceinline__ float sigm(float x) { return 1.f / (1.f + __expf(-x)); }
__device__ __forceinline__ float tanhf_(float x) { return 1.f - 2.f / (__expf(2.f * x) + 1.f); }

// agent-coherent (MALL-served) 8B store for cross-block h exchange
__device__ __forceinline__ void st_agent_u64(float* p, float a, float b) {
  union { float f[2]; unsigned long long u; } v;
  v.f[0] = a; v.f[1] = b;
  __hip_atomic_store((unsigned long long*)p, v.u, __ATOMIC_RELAXED, __HIP_MEMORY_SCOPE_AGENT);
}

// ---------- K0: Wih (f|b concat [2048][256]) and W_emit ([16][512], rows>=9 zero) -> bf16 hi/lo ----------
__global__ __launch_bounds__(256) void k_prep_w(const float* __restrict__ wf, const float* __restrict__ wb,
                                                const float* __restrict__ we,
                                                u16* __restrict__ wihh, u16* __restrict__ wihl,
                                                u16* __restrict__ weh, u16* __restrict__ wel) {
  int i = blockIdx.x * 256 + threadIdx.x;
  float v; u16 *dh, *dl; int o;
  if (i < 524288) {
    int g = i >> 8, k = i & 255;
    v = (g < 1024) ? wf[g * 256 + k] : wb[(g - 1024) * 256 + k];
    dh = wihh; dl = wihl; o = i;
  } else {
    int j = i - 524288;
    int r = j >> 9, k = j & 511;
    v = (r < 9) ? we[r * 512 + k] : 0.f;
    dh = weh; dl = wel; o = j;
  }
  u16 hh = f2bf(v);
  dh[o] = hh; dl[o] = f2bf(v - bf2f(hh));
}

// ---------- K1: chunked input GEMM ----------
__global__ __launch_bounds__(256) void k_gemm_in(const int* __restrict__ ix,
    const float* __restrict__ emb,
    const u16* __restrict__ wh, const u16* __restrict__ wl,
    const float* __restrict__ bf_, const float* __restrict__ bb_,
    float* __restrict__ xw, int c0step, int S, int logS) {
  int w = threadIdx.x >> 6, l = threadIdx.x & 63;
  int la = l & 15, lk = (l >> 4) * 8;
  int dir = blockIdx.z;
  int m0 = blockIdx.x * 64 + w * 16;
  int n0 = blockIdx.y * 128;
  int mA = m0 + la;
  int bA = mA >> logS, slA = mA & (S - 1);
  int sg = c0step + slA;
  int tA = dir ? (127 - sg) : sg;
  const float* erow = emb + (long)ix[bA * 128 + tA] * 256;
  f32x4 acc[8];
#pragma unroll
  for (int i = 0; i < 8; ++i) acc[i] = (f32x4){0.f, 0.f, 0.f, 0.f};
#pragma unroll
  for (int ks = 0; ks < 8; ++ks) {
    int k = ks * 32 + lk;
    f32x4 v0 = *(const f32x4*)(erow + k);
    f32x4 v1 = *(const f32x4*)(erow + k + 4);
    bf16x8 ah, al;
    split8v(v0, v1, ah, al);
#pragma unroll
    for (int nt = 0; nt < 8; ++nt) {
      int g = n0 + nt * 16 + la;
      long go = (long)(dir * 1024 + g) * 256 + k;
      bf16x8 bh = *(const bf16x8*)(wh + go);
      bf16x8 bl = *(const bf16x8*)(wl + go);
      acc[nt] = __builtin_amdgcn_mfma_f32_16x16x32_bf16(ah, bh, acc[nt], 0, 0, 0);
      acc[nt] = __builtin_amdgcn_mfma_f32_16x16x32_bf16(ah, bl, acc[nt], 0, 0, 0);
      acc[nt] = __builtin_amdgcn_mfma_f32_16x16x32_bf16(al, bh, acc[nt], 0, 0, 0);
    }
  }
  int mrb = m0 + (l >> 4) * 4;
#pragma unroll
  for (int nt = 0; nt < 8; ++nt) {
    int g = n0 + nt * 16 + la;
    float bias = (dir ? bb_ : bf_)[g];
#pragma unroll
    for (int r = 0; r < 4; ++r) {
      int m2 = mrb + r;
      int b2 = m2 >> logS, sl2 = m2 & (S - 1);
      xw[((long)(dir * 256 + b2) * S + sl2) * 1024 + g] = acc[nt][r] + bias;
    }
  }
}

// ---------- K2: BiLSTM recurrence (chunk of S steps) ----------
// 256 blocks = 2 dir x 16 batch-slices x 8 j-slices; Whh slice (hi+lo bf16) resident in LDS.
// h exchange: coalesced sc0/sc1 (MALL-coherent) wide loads staged through LDS; write-through stores;
// per-wave flag signaling (count to 32 = 8 blocks x 4 waves).
#define LW 264
#define HSTR 260
__global__ __launch_bounds__(256) void k_lstm(
    const float* __restrict__ whh_f, const float* __restrict__ whh_b,
    const float* __restrict__ h0f, const float* __restrict__ c0f,
    const float* __restrict__ h0b, const float* __restrict__ c0b,
    const float* __restrict__ xw,
    float* __restrict__ hf, float* __restrict__ hb,
    float* __restrict__ cstate, unsigned* __restrict__ flags,
    int s0, int S, int first, int last) {
  __shared__ u16 wlh[128 * LW];
  __shared__ u16 wll[128 * LW];
  __shared__ float gl[16 * 132];
  __shared__ float hst[16 * HSTR];
  int bid = blockIdx.x;
  int js = (bid >> 3) & 7;
  int G = ((bid >> 6) << 3) | (bid & 7);   // group id; members share blockIdx%8
  int dir = G >> 4, bs = G & 15;
  const float* whh = dir ? whh_b : whh_f;
  float* hout = dir ? hb : hf;
  int tid = threadIdx.x;
  for (int i = 0; i < 128; ++i) {
    int q = i >> 5, u = i & 31;
    int gate = q * 256 + js * 32 + u;
    float v = whh[gate * 256 + tid];
    u16 hh = f2bf(v);
    wlh[i * LW + tid] = hh;
    wll[i * LW + tid] = f2bf(v - bf2f(hh));
  }
  int b_l = tid >> 4, jj = tid & 15;
  int b_g = bs * 16 + b_l;
  int jg0 = js * 32 + jj * 2;
  float cv0, cv1;
  if (first) {
    const float* c0 = dir ? c0b : c0f;
    cv0 = c0[b_g * 256 + jg0];
    cv1 = c0[b_g * 256 + jg0 + 1];
  } else {
    cv0 = cstate[(dir * 256 + b_g) * 256 + jg0];
    cv1 = cstate[(dir * 256 + b_g) * 256 + jg0 + 1];
  }
  int w = tid >> 6, l = tid & 63, la = l & 15, lk = (l >> 4) * 8;
  int srow = tid >> 4, sc0_ = (tid & 15) * 16;   // staging row/col for this thread
  const float* h0 = dir ? h0b : h0f;
  __syncthreads();
  for (int sl = 0; sl < S; ++sl) {
    int sg = s0 + sl;
    int t_io = dir ? 127 - sg : sg;
    // xw prefetch for this step (independent of flags; in flight during poll)
    long xrow = ((long)(dir * 256 + b_g) * S + sl) * 1024 + jg0;
    float2 xi = *(const float2*)(xw + xrow);
    float2 xf = *(const float2*)(xw + xrow + 256);
    float2 xg = *(const float2*)(xw + xrow + 512);
    float2 xo = *(const float2*)(xw + xrow + 768);
    // wait for previous step's h (32 signals = 8 blocks x 4 waves); doubles as intra-block sync
    if (sl > 0) {
      if ((tid & 63) == 0) {
        const unsigned* fl = &flags[((sg - 1) * 32 + G) * 32];
        int guard = 0;
        while (__hip_atomic_load(fl, __ATOMIC_RELAXED, __HIP_MEMORY_SCOPE_AGENT) < 32u
               && ++guard < (1 << 26)) {}
      }
    }
    // cooperative coherent stage: block's 16-row h slice -> LDS (coalesced MALL reads)
    {
      const float* p;
      if (sg == 0) p = h0 + (bs * 16 + srow) * 256 + sc0_;
      else { int tp = dir ? t_io + 1 : t_io - 1; p = hout + ((long)(bs * 16 + srow) * 128 + tp) * 256 + sc0_; }
      f32x4 r0, r1, r2, r3;
      asm volatile(
        "global_load_dwordx4 %0, %4, off sc0 sc1\n\t"
        "global_load_dwordx4 %1, %4, off offset:16 sc0 sc1\n\t"
        "global_load_dwordx4 %2, %4, off offset:32 sc0 sc1\n\t"
        "global_load_dwordx4 %3, %4, off offset:48 sc0 sc1\n\t"
        "s_waitcnt vmcnt(0)"
        : "=v"(r0), "=v"(r1), "=v"(r2), "=v"(r3)
        : "v"(p)
        : "memory");
      float* d = &hst[srow * HSTR + sc0_];
      *(f32x4*)(d) = r0; *(f32x4*)(d + 4) = r1;
      *(f32x4*)(d + 8) = r2; *(f32x4*)(d + 12) = r3;
    }
    __syncthreads();   // (C) stage complete; also orders prev epilogue vs new gl writes
    // MFMA from LDS-staged h fragments
    f32x4 a0 = (f32x4){0.f,0.f,0.f,0.f}, a1 = (f32x4){0.f,0.f,0.f,0.f};
    const float* hrow = &hst[la * HSTR];
#pragma unroll
    for (int ks = 0; ks < 8; ++ks) {
      int k = ks * 32 + lk;
      f32x4 v0 = *(const f32x4*)(hrow + k);
      f32x4 v1 = *(const f32x4*)(hrow + k + 4);
      bf16x8 ah, al;
      split8v(v0, v1, ah, al);
      {
        int row = w * 32 + la;
        bf16x8 bh = *(const bf16x8*)(wlh + row * LW + k);
        bf16x8 bl = *(const bf16x8*)(wll + row * LW + k);
        a0 = __builtin_amdgcn_mfma_f32_16x16x32_bf16(ah, bh, a0, 0, 0, 0);
        a0 = __builtin_amdgcn_mfma_f32_16x16x32_bf16(ah, bl, a0, 0, 0, 0);
        a0 = __builtin_amdgcn_mfma_f32_16x16x32_bf16(al, bh, a0, 0, 0, 0);
      }
      {
        int row = w * 32 + 16 + la;
        bf16x8 bh = *(const bf16x8*)(wlh + row * LW + k);
        bf16x8 bl = *(const bf16x8*)(wll + row * LW + k);
        a1 = __builtin_amdgcn_mfma_f32_16x16x32_bf16(ah, bh, a1, 0, 0, 0);
        a1 = __builtin_amdgcn_mfma_f32_16x16x32_bf16(ah, bl, a1, 0, 0, 0);
        a1 = __builtin_amdgcn_mfma_f32_16x16x32_bf16(al, bh, a1, 0, 0, 0);
      }
    }
#pragma unroll
    for (int r = 0; r < 4; ++r) {
      gl[((l >> 4) * 4 + r) * 132 + w * 32 + la] = a0[r];
      gl[((l >> 4) * 4 + r) * 132 + w * 32 + 16 + la] = a1[r];
    }
    __syncthreads();   // (A) gl exchange complete
    float hv0, hv1;
    {
      int jl = jj * 2;
      float gi = gl[b_l * 132 + jl]      + xi.x;
      float gf = gl[b_l * 132 + 32 + jl] + xf.x;
      float gg = gl[b_l * 132 + 64 + jl] + xg.x;
      float go = gl[b_l * 132 + 96 + jl] + xo.x;
      float c = sigm(gf) * cv0 + sigm(gi) * tanhf_(gg);
      cv0 = c; hv0 = sigm(go) * tanhf_(c);
    }
    {
      int jl = jj * 2 + 1;
      float gi = gl[b_l * 132 + jl]      + xi.y;
      float gf = gl[b_l * 132 + 32 + jl] + xf.y;
      float gg = gl[b_l * 132 + 64 + jl] + xg.y;
      float go = gl[b_l * 132 + 96 + jl] + xo.y;
      float c = sigm(gf) * cv1 + sigm(gi) * tanhf_(gg);
      cv1 = c; hv1 = sigm(go) * tanhf_(c);
    }
    st_agent_u64(hout + ((long)b_g * 128 + t_io) * 256 + jg0, hv0, hv1);
    asm volatile("s_waitcnt vmcnt(0)" ::: "memory");   // per-wave drain before signaling
    if ((tid & 63) == 0)
      __hip_atomic_fetch_add(&flags[(sg * 32 + G) * 32], 1u,
                             __ATOMIC_RELAXED, __HIP_MEMORY_SCOPE_AGENT);
    // no trailing barrier: next iteration's poll (to 32) orders all waves/blocks
  }
  if (!last) {
    cstate[(dir * 256 + b_g) * 256 + jg0] = cv0;
    cstate[(dir * 256 + b_g) * 256 + jg0 + 1] = cv1;
  }
}

// ---------- K3: emission  emis[m][16] = [hf|hb] @ W_emit^T + b_emit ----------
__global__ __launch_bounds__(256) void k_emis(const float* __restrict__ hf, const float* __restrict__ hb,
    const u16* __restrict__ weh, const u16* __restrict__ wel,
    const float* __restrict__ bemit, float* __restrict__ emis) {
  int w = threadIdx.x >> 6, l = threadIdx.x & 63;
  int la = l & 15, lk = (l >> 4) * 8;
  long m0 = (long)blockIdx.x * 64 + w * 16;
  long am = m0 + la;
  f32x4 acc = (f32x4){0.f, 0.f, 0.f, 0.f};
#pragma unroll
  for (int ks = 0; ks < 16; ++ks) {
    int k = ks * 32 + lk;
    const float* src = (k < 256) ? (hf + am * 256 + k) : (hb + am * 256 + (k - 256));
    f32x4 v0 = *(const f32x4*)src;
    f32x4 v1 = *(const f32x4*)(src + 4);
    bf16x8 ah, al;
    split8v(v0, v1, ah, al);
    bf16x8 bh = *(const bf16x8*)(weh + la * 512 + k);
    bf16x8 bl = *(const bf16x8*)(wel + la * 512 + k);
    acc = __builtin_amdgcn_mfma_f32_16x16x32_bf16(ah, bh, acc, 0, 0, 0);
    acc = __builtin_amdgcn_mfma_f32_16x16x32_bf16(ah, bl, acc, 0, 0, 0);
    acc = __builtin_amdgcn_mfma_f32_16x16x32_bf16(al, bh, acc, 0, 0, 0);
  }
  int kout = la;
  float bias = (kout < 9) ? bemit[kout] : 0.f;
  long mr = m0 + (l >> 4) * 4;
#pragma unroll
  for (int r = 0; r < 4; ++r)
    emis[(mr + r) * 16 + kout] = acc[r] + bias;
}

// ---------- K4: CRF forward (logZ) + gold-path numerator ----------
__global__ __launch_bounds__(256) void k_crf(const float* __restrict__ emis, const int* __restrict__ ixin,
    const int* __restrict__ label, const float* __restrict__ startt, const float* __restrict__ endt,
    const float* __restrict__ trans, float* __restrict__ lossp) {
  __shared__ float al_s[16][16];
  __shared__ float tr_s[9][16];
  __shared__ float num_s[16];
  __shared__ float red_s[16];
  int tid = threadIdx.x, bl = tid >> 4, k = tid & 15;
  int b = blockIdx.x * 16 + bl;
  if (bl < 9) tr_s[bl][k] = (k < 9) ? trans[bl * 9 + k] : 0.f;
  float a = 0.f, num = 0.f;
  int lastlab = 0;
  if (k < 9) a = startt[k] + emis[((long)b * 128) * 16 + k];
  al_s[bl][k] = a;
  if (k == 9) {
    int l0 = label[b * 128];
    num = startt[l0] + emis[((long)b * 128) * 16 + l0];
    lastlab = l0;
  }
  __syncthreads();
  for (int t = 1; t < 128; ++t) {
    bool msk = ixin[b * 128 + t] != 0;
    float anew = a;
    if (k < 9) {
      float mx = -1e30f;
#pragma unroll
      for (int j = 0; j < 9; ++j) mx = fmaxf(mx, al_s[bl][j] + tr_s[j][k]);
      float ss = 0.f;
#pragma unroll
      for (int j = 0; j < 9; ++j) ss += __expf(al_s[bl][j] + tr_s[j][k] - mx);
      anew = mx + __logf(ss) + emis[((long)b * 128 + t) * 16 + k];
      if (!msk) anew = a;
    } else if (k == 9 && msk) {
      int lt = label[b * 128 + t];
      num += tr_s[lastlab][lt] + emis[((long)b * 128 + t) * 16 + lt];
      lastlab = lt;
    }
    __syncthreads();
    if (k < 9) { a = anew; al_s[bl][k] = a; }
    __syncthreads();
  }
  if (k == 9) num_s[bl] = num + endt[lastlab];
  __syncthreads();
  if (k == 0) {
    float mx = -1e30f;
#pragma unroll
    for (int j = 0; j < 9; ++j) mx = fmaxf(mx, al_s[bl][j] + endt[j]);
    float ss = 0.f;
#pragma unroll
    for (int j = 0; j < 9; ++j) ss += __expf(al_s[bl][j] + endt[j] - mx);
    red_s[bl] = (mx + __logf(ss)) - num_s[bl];
  }
  __syncthreads();
  if (tid == 0) {
    float s = 0.f;
    for (int i = 0; i < 16; ++i) s += red_s[i];
    lossp[blockIdx.x] = s;
  }
}

// ---------- K5: Viterbi forward storing backpointers ----------
__global__ __launch_bounds__(256) void k_vit(const float* __restrict__ emis,
    const float* __restrict__ startt, const float* __restrict__ trans,
    unsigned char* __restrict__ bp, float* __restrict__ vfin) {
  __shared__ float al_s[16][16];
  __shared__ float tr_s[9][16];
  int tid = threadIdx.x, bl = tid >> 4, k = tid & 15;
  int b = blockIdx.x * 16 + bl;
  if (bl < 9) tr_s[bl][k] = (k < 9) ? trans[bl * 9 + k] : 0.f;
  float v = -1e30f;
  if (k < 9) v = startt[k] + emis[((long)b * 128) * 16 + k];
  al_s[bl][k] = v;
  __syncthreads();
  for (int t = 1; t < 128; ++t) {
    float vnew = v;
    if (k < 9) {
      float best = -1e30f; int bi = 0;
#pragma unroll
      for (int j = 0; j < 9; ++j) {
        float tot = al_s[bl][j] + tr_s[j][k];
        if (tot > best) { best = tot; bi = j; }
      }
      vnew = best + emis[((long)b * 128 + t) * 16 + k];
      bp[((long)b * 127 + (t - 1)) * 16 + k] = (unsigned char)bi;
    }
    __syncthreads();
    if (k < 9) { v = vnew; al_s[bl][k] = v; }
    __syncthreads();
  }
  vfin[b * 16 + k] = (k < 9) ? v : -1e30f;
}

// ---------- K6: backtrace (LDS-staged) + loss reduction ----------
__global__ __launch_bounds__(256) void k_fin(const float* __restrict__ vfin, const float* __restrict__ endt,
    const unsigned char* __restrict__ bp, const float* __restrict__ lossp, float* __restrict__ out) {
  __shared__ unsigned char bpl[16 * 127 * 16];
  int tid = threadIdx.x;
  const unsigned* src = (const unsigned*)(bp + (long)blockIdx.x * 32512);
  unsigned* dst = (unsigned*)bpl;
  for (int i = tid; i < 8128; i += 256) dst[i] = src[i];
  __syncthreads();
  if (tid < 16) {
    int b = blockIdx.x * 16 + tid;
    float best = -1e30f; int tag = 0;
#pragma unroll
    for (int j = 0; j < 9; ++j) {
      float v = vfin[b * 16 + j] + endt[j];
      if (v > best) { best = v; tag = j; }
    }
    out[1 + b * 128 + 127] = (float)tag;
    for (int t = 127; t >= 1; --t) {
      tag = bpl[(tid * 127 + (t - 1)) * 16 + tag];
      out[1 + b * 128 + t - 1] = (float)tag;
    }
  }
  if (blockIdx.x == 0 && tid == 0) {
    float s = 0.f;
    for (int i = 0; i < 16; ++i) s += lossp[i];
    out[0] = s;
  }
}

__global__ void k_sent(float* out) { out[0] = -1.0e6f; }

// ---------- launch ----------
extern "C" void kernel_launch(void* const* d_in, const int* in_sizes, int n_in,
                              void* d_out, int out_size, void* d_ws, size_t ws_size,
                              hipStream_t stream) {
  const int* in_x    = (const int*)d_in[0];
  const int* label   = (const int*)d_in[1];
  const float* emb   = (const float*)d_in[2];
  const float* Wih_f = (const float*)d_in[3];
  const float* Whh_f = (const float*)d_in[4];
  const float* b_f   = (const float*)d_in[5];
  const float* Wih_b = (const float*)d_in[6];
  const float* Whh_b = (const float*)d_in[7];
  const float* b_b   = (const float*)d_in[8];
  const float* W_emit= (const float*)d_in[9];
  const float* b_emit= (const float*)d_in[10];
  const float* start_t=(const float*)d_in[11];
  const float* end_t = (const float*)d_in[12];
  const float* trans = (const float*)d_in[13];
  const float* h0f   = (const float*)d_in[14];
  const float* c0f   = (const float*)d_in[15];
  const float* h0b   = (const float*)d_in[16];
  const float* c0b   = (const float*)d_in[17];
  (void)in_sizes; (void)n_in; (void)out_size;

  auto align = [](size_t x) { return (x + 255) & ~(size_t)255; };
  size_t fixed = 0;
  fixed += align(32768L * 256 * 4);        // HF
  fixed += align(32768L * 256 * 4);        // HB
  fixed += align(2048L * 256 * 2);         // WIHH
  fixed += align(2048L * 256 * 2);         // WIHL
  fixed += align(16L * 512 * 2);           // WEH
  fixed += align(16L * 512 * 2);           // WEL
  fixed += align(32768L * 16 * 4);         // EMIS
  fixed += align(256L * 127 * 16);         // BP
  fixed += align(256L * 16 * 4);           // VFIN
  fixed += align(64 * 4);                  // LOSSP
  fixed += align(128L * 32 * 32 * 4);      // FLAGS (128B-padded per group/step)
  fixed += align(2L * 256 * 256 * 4);      // CSTATE

  int S = 0;
  const int cands[4] = {128, 64, 32, 16};
  for (int ci = 0; ci < 4; ++ci) {
    size_t xb = align(2097152L * cands[ci]);
    if (xb + fixed <= ws_size) { S = cands[ci]; break; }
  }
  if (S == 0) { k_sent<<<1, 1, 0, stream>>>((float*)d_out); return; }
  int logS = __builtin_ctz(S);
  int NC = 128 / S;

  char* ws = (char*)d_ws;
  size_t o = 0;
  auto alloc = [&](size_t sz) { size_t r = o; o += (sz + 255) & ~(size_t)255; return r; };
  float* xw   = (float*)(ws + alloc(2097152L * S));
  float* hf   = (float*)(ws + alloc(32768L * 256 * 4));
  float* hb   = (float*)(ws + alloc(32768L * 256 * 4));
  u16* wihh   = (u16*)(ws + alloc(2048L * 256 * 2));
  u16* wihl   = (u16*)(ws + alloc(2048L * 256 * 2));
  u16* weh    = (u16*)(ws + alloc(16L * 512 * 2));
  u16* wel    = (u16*)(ws + alloc(16L * 512 * 2));
  float* emis = (float*)(ws + alloc(32768L * 16 * 4));
  unsigned char* bp = (unsigned char*)(ws + alloc(256L * 127 * 16));
  float* vfin = (float*)(ws + alloc(256L * 16 * 4));
  float* lossp= (float*)(ws + alloc(64 * 4));
  unsigned* flags = (unsigned*)(ws + alloc(128L * 32 * 32 * 4));
  float* cstate = (float*)(ws + alloc(2L * 256 * 256 * 4));

  hipMemsetAsync(flags, 0, 128L * 32 * 32 * 4, stream);
  k_prep_w<<<2080, 256, 0, stream>>>(Wih_f, Wih_b, W_emit, wihh, wihl, weh, wel);
  for (int c = 0; c < NC; ++c) {
    k_gemm_in<<<dim3(4 * S, 8, 2), 256, 0, stream>>>(in_x, emb, wihh, wihl, b_f, b_b,
                                                     xw, c * S, S, logS);
    k_lstm<<<256, 256, 0, stream>>>(Whh_f, Whh_b, h0f, c0f, h0b, c0b, xw, hf, hb,
                                    cstate, flags, c * S, S, c == 0 ? 1 : 0, c == NC - 1 ? 1 : 0);
  }
  k_emis<<<512, 256, 0, stream>>>(hf, hb, weh, wel, b_emit, emis);
  k_crf<<<16, 256, 0, stream>>>(emis, in_x, label, start_t, end_t, trans, lossp);
  k_vit<<<16, 256, 0, stream>>>(emis, start_t, trans, bp, vfin);
  k_fin<<<16, 256, 0, stream>>>(vfin, end_t, bp, lossp, (float*)d_out);
}

// Round 5
// 493.068 us; speedup vs baseline: 6.2074x; 2.3815x over previous
//
#include <hip/hip_runtime.h>

typedef __attribute__((ext_vector_type(8))) short bf16x8;
typedef __attribute__((ext_vector_type(4))) float f32x4;
typedef __attribute__((ext_vector_type(4))) unsigned u32x4;
typedef unsigned short u16;

#define SENT 0xC1C1C1C1u

// ---------- helpers ----------
__device__ __forceinline__ u16 f2bf(float f) {
  union { float f; unsigned u; } v; v.f = f;
  unsigned r = v.u + 0x7fffu + ((v.u >> 16) & 1u);
  return (u16)(r >> 16);
}
__device__ __forceinline__ unsigned cvt_pk(float lo, float hi) {
  unsigned r;
  asm("v_cvt_pk_bf16_f32 %0, %1, %2" : "=v"(r) : "v"(lo), "v"(hi));
  return r;
}
__device__ __forceinline__ float bflo(unsigned d) { return __uint_as_float(d << 16); }
__device__ __forceinline__ float bfhi(unsigned d) { return __uint_as_float(d & 0xffff0000u); }
__device__ __forceinline__ float sigm(float x) { return 1.f / (1.f + __expf(-x)); }
__device__ __forceinline__ float tanhf_(float x) { return 1.f - 2.f / (__expf(2.f * x) + 1.f); }

// ---------- K0: one-pass f32 -> bf16 prep (emb | Wih f,b | W_emit padded to 16 rows) ----------
// layout: ebh[30000*256]; wihh[2][1024][256]; weh[16][512]
__global__ __launch_bounds__(256) void k_prep(const float* __restrict__ emb,
    const float* __restrict__ wf, const float* __restrict__ wb, const float* __restrict__ we,
    u16* __restrict__ ebh, u16* __restrict__ wihh, u16* __restrict__ weh) {
  int i4 = (blockIdx.x * 256 + threadIdx.x) * 4;
  const float* src; u16* dst; int o;
  float z0 = 0.f, z1 = 0.f, z2 = 0.f, z3 = 0.f;
  bool zero = false;
  if (i4 < 7680000) { src = emb + i4; dst = ebh; o = i4; }
  else if (i4 < 8204288) {
    int off = i4 - 7680000;
    src = (off < 262144) ? (wf + off) : (wb + off - 262144);
    dst = wihh; o = off;
  } else {
    int off = i4 - 8204288;
    int r = off >> 9, k = off & 511;
    dst = weh; o = off;
    if (r < 9) src = we + r * 512 + k; else { zero = true; src = we; }
  }
  f32x4 v = zero ? (f32x4){z0, z1, z2, z3} : *(const f32x4*)src;
  unsigned q0 = cvt_pk(v[0], v[1]);
  unsigned q1 = cvt_pk(v[2], v[3]);
  *(unsigned*)(dst + o) = q0;
  *(unsigned*)(dst + o + 2) = q1;
}

// ---------- K1: chunked input GEMM (bf16, B tile LDS-staged with XOR swizzle) ----------
// grid (2*S, 8, 2), block 256 (4 waves): tile M=128 tokens x N=128 gates, K=256.
__global__ __launch_bounds__(256) void k_gemm_in(const int* __restrict__ ix,
    const u16* __restrict__ ebh, const u16* __restrict__ wihh,
    const float* __restrict__ bf_, const float* __restrict__ bb_,
    u16* __restrict__ xw, int c0step, int S, int logS) {
  __shared__ __align__(16) char smraw[128 * 132 * 4];
  int tid = threadIdx.x;
  int w = tid >> 6, l = tid & 63, la = l & 15, lk = (l >> 4) * 8;
  int dir = blockIdx.z;
  int m0 = blockIdx.x * 128;
  int n0 = blockIdx.y * 128;
  // stage B tile: 128 gates x 256 k bf16 = 64KB, swizzled LDS writes, linear global reads
  const char* gB = (const char*)(wihh + ((long)(dir * 1024 + n0) << 8));
#pragma unroll
  for (int it = 0; it < 16; ++it) {
    int y = it * 4096 + tid * 16;
    int sw = y ^ (((y >> 9) & 7) << 4);
    *(u32x4*)(smraw + sw) = *(const u32x4*)(gB + y);
  }
  long arow[2];
#pragma unroll
  for (int mf = 0; mf < 2; ++mf) {
    int mA = m0 + w * 32 + mf * 16 + la;
    int bA = mA >> logS, slA = mA & (S - 1);
    int sg = c0step + slA;
    int tA = dir ? (127 - sg) : sg;
    arow[mf] = (long)ix[bA * 128 + tA] << 8;
  }
  int gb[8], gx[8];
#pragma unroll
  for (int nt = 0; nt < 8; ++nt) { int g = nt * 16 + la; gb[nt] = g * 512; gx[nt] = (g & 7) << 4; }
  __syncthreads();
  f32x4 acc[2][8];
#pragma unroll
  for (int mf = 0; mf < 2; ++mf)
#pragma unroll
    for (int nt = 0; nt < 8; ++nt) acc[mf][nt] = (f32x4){0.f, 0.f, 0.f, 0.f};
#pragma unroll
  for (int ks = 0; ks < 8; ++ks) {
    int k = ks * 32 + lk;
    int kb = 2 * k;
    bf16x8 a0 = *(const bf16x8*)(ebh + arow[0] + k);
    bf16x8 a1 = *(const bf16x8*)(ebh + arow[1] + k);
#pragma unroll
    for (int nt = 0; nt < 8; ++nt) {
      bf16x8 bh = *(const bf16x8*)(smraw + gb[nt] + (kb ^ gx[nt]));
      acc[0][nt] = __builtin_amdgcn_mfma_f32_16x16x32_bf16(a0, bh, acc[0][nt], 0, 0, 0);
      acc[1][nt] = __builtin_amdgcn_mfma_f32_16x16x32_bf16(a1, bh, acc[1][nt], 0, 0, 0);
    }
  }
  __syncthreads();   // B reads done; reuse LDS as f32 out-tile [128][132]
  float* ot = (float*)smraw;
#pragma unroll
  for (int mf = 0; mf < 2; ++mf)
#pragma unroll
    for (int nt = 0; nt < 8; ++nt)
#pragma unroll
      for (int r = 0; r < 4; ++r)
        ot[(w * 32 + mf * 16 + (l >> 4) * 4 + r) * 132 + nt * 16 + la] = acc[mf][nt][r];
  __syncthreads();
  // pack + bias -> coalesced bf16 rows
  const float* bias = (dir ? bb_ : bf_) + n0;
  long MSd = (long)256 * S * 1024;
  int m_r0 = tid >> 4;
  int cc = (tid & 15) * 8;
  f32x4 b0 = *(const f32x4*)(bias + cc);
  f32x4 b1 = *(const f32x4*)(bias + cc + 4);
#pragma unroll
  for (int it = 0; it < 8; ++it) {
    int m_r = it * 16 + m_r0;
    f32x4 v0 = *(const f32x4*)&ot[m_r * 132 + cc];
    f32x4 v1 = *(const f32x4*)&ot[m_r * 132 + cc + 4];
    u32x4 q;
    q[0] = cvt_pk(v0[0] + b0[0], v0[1] + b0[1]);
    q[1] = cvt_pk(v0[2] + b0[2], v0[3] + b0[3]);
    q[2] = cvt_pk(v1[0] + b1[0], v1[1] + b1[1]);
    q[3] = cvt_pk(v1[2] + b1[2], v1[3] + b1[3]);
    *(u32x4*)(xw + dir * MSd + (long)(m0 + m_r) * 1024 + n0 + cc) = q;
  }
}

// ---------- K2: BiLSTM recurrence, sentinel-dataflow cross-block sync ----------
// 256 blocks = 2 dir x 16 batch-slices x 8 j-slices; Whh slice bf16 resident in LDS.
#define LW 264
__global__ __launch_bounds__(256) void k_lstm(
    const float* __restrict__ whh_f, const float* __restrict__ whh_b,
    const float* __restrict__ h0f, const float* __restrict__ c0f,
    const float* __restrict__ h0b, const float* __restrict__ c0b,
    const u16* __restrict__ xwp,
    u16* __restrict__ hf, u16* __restrict__ hb,
    float* __restrict__ cstate,
    int s0, int S, int first, int last) {
  __shared__ u16 wlh[128 * LW];
  __shared__ u16 hst[16 * LW];
  __shared__ float gl[16 * 132];
  int bid = blockIdx.x;
  int js = (bid >> 3) & 7;
  int G = ((bid >> 6) << 3) | (bid & 7);
  int dir = G >> 4, bs = G & 15;
  const float* whh = dir ? whh_b : whh_f;
  u16* hout = dir ? hb : hf;
  int tid = threadIdx.x;
  for (int i = 0; i < 128; ++i) {
    int q = i >> 5, u = i & 31;
    int gate = q * 256 + js * 32 + u;
    wlh[i * LW + tid] = f2bf(whh[gate * 256 + tid]);
  }
  int b_l = tid >> 4, jj = tid & 15;
  int b_g = bs * 16 + b_l;
  int jg0 = js * 32 + jj * 2;
  float cv0, cv1;
  if (first) {
    const float* c0 = dir ? c0b : c0f;
    cv0 = c0[b_g * 256 + jg0];
    cv1 = c0[b_g * 256 + jg0 + 1];
  } else {
    cv0 = cstate[(dir * 256 + b_g) * 256 + jg0];
    cv1 = cstate[(dir * 256 + b_g) * 256 + jg0 + 1];
  }
  int w = tid >> 6, l = tid & 63, la = l & 15, lk = (l >> 4) * 8;
  int srow = tid >> 4, scol = (tid & 15) * 16;
  const float* h0 = dir ? h0b : h0f;
  long MSd = (long)256 * S * 1024;
  __syncthreads();
  for (int sl = 0; sl < S; ++sl) {
    int sg = s0 + sl;
    int t_io = dir ? 127 - sg : sg;
    // xw prefetch (normal cached loads, in flight during poll)
    long xbase = (long)dir * MSd + ((long)b_g * S + sl) * 1024 + jg0;
    unsigned dI = *(const unsigned*)(xwp + xbase);
    unsigned dF = *(const unsigned*)(xwp + xbase + 256);
    unsigned dG = *(const unsigned*)(xwp + xbase + 512);
    unsigned dO = *(const unsigned*)(xwp + xbase + 768);
    // stage h(t prev) -> LDS
    u16* hd = &hst[srow * LW + scol];
    if (sg == 0) {
      const float* p = h0 + (bs * 16 + srow) * 256 + scol;
      f32x4 v0 = *(const f32x4*)p, v1 = *(const f32x4*)(p + 4);
      f32x4 v2 = *(const f32x4*)(p + 8), v3 = *(const f32x4*)(p + 12);
      u32x4 qa, qb;
      qa[0] = cvt_pk(v0[0], v0[1]); qa[1] = cvt_pk(v0[2], v0[3]);
      qa[2] = cvt_pk(v1[0], v1[1]); qa[3] = cvt_pk(v1[2], v1[3]);
      qb[0] = cvt_pk(v2[0], v2[1]); qb[1] = cvt_pk(v2[2], v2[3]);
      qb[2] = cvt_pk(v3[0], v3[1]); qb[3] = cvt_pk(v3[2], v3[3]);
      *(u32x4*)hd = qa; *((u32x4*)hd + 1) = qb;
    } else {
      int tp = dir ? t_io + 1 : t_io - 1;
      const u16* p = hout + ((long)(bs * 16 + srow) * 128 + tp) * 256 + scol;
      u32x4 r0, r1; int guard = 0; bool ok;
      do {
        asm volatile(
          "global_load_dwordx4 %0, %2, off sc0 sc1\n\t"
          "global_load_dwordx4 %1, %2, off offset:16 sc0 sc1\n\t"
          "s_waitcnt vmcnt(0)"
          : "=v"(r0), "=v"(r1) : "v"(p) : "memory");
        ok = (r0[0] != SENT) & (r0[1] != SENT) & (r0[2] != SENT) & (r0[3] != SENT)
           & (r1[0] != SENT) & (r1[1] != SENT) & (r1[2] != SENT) & (r1[3] != SENT);
      } while (__builtin_expect(!ok, 0) && ++guard < (1 << 22));
      *(u32x4*)hd = r0; *((u32x4*)hd + 1) = r1;
    }
    __syncthreads();
    f32x4 a0 = (f32x4){0.f, 0.f, 0.f, 0.f}, a1 = (f32x4){0.f, 0.f, 0.f, 0.f};
#pragma unroll
    for (int ks = 0; ks < 8; ++ks) {
      int k = ks * 32 + lk;
      bf16x8 ah = *(const bf16x8*)&hst[la * LW + k];
      bf16x8 b0 = *(const bf16x8*)&wlh[(w * 32 + la) * LW + k];
      bf16x8 b1 = *(const bf16x8*)&wlh[(w * 32 + 16 + la) * LW + k];
      a0 = __builtin_amdgcn_mfma_f32_16x16x32_bf16(ah, b0, a0, 0, 0, 0);
      a1 = __builtin_amdgcn_mfma_f32_16x16x32_bf16(ah, b1, a1, 0, 0, 0);
    }
#pragma unroll
    for (int r = 0; r < 4; ++r) {
      gl[((l >> 4) * 4 + r) * 132 + w * 32 + la] = a0[r];
      gl[((l >> 4) * 4 + r) * 132 + w * 32 + 16 + la] = a1[r];
    }
    __syncthreads();
    float hv0, hv1;
    {
      int jl = jj * 2;
      float gi = gl[b_l * 132 + jl]      + bflo(dI);
      float gf = gl[b_l * 132 + 32 + jl] + bflo(dF);
      float gg = gl[b_l * 132 + 64 + jl] + bflo(dG);
      float go = gl[b_l * 132 + 96 + jl] + bflo(dO);
      float c = sigm(gf) * cv0 + sigm(gi) * tanhf_(gg);
      cv0 = c; hv0 = sigm(go) * tanhf_(c);
    }
    {
      int jl = jj * 2 + 1;
      float gi = gl[b_l * 132 + jl]      + bfhi(dI);
      float gf = gl[b_l * 132 + 32 + jl] + bfhi(dF);
      float gg = gl[b_l * 132 + 64 + jl] + bfhi(dG);
      float go = gl[b_l * 132 + 96 + jl] + bfhi(dO);
      float c = sigm(gf) * cv1 + sigm(gi) * tanhf_(gg);
      cv1 = c; hv1 = sigm(go) * tanhf_(c);
    }
    unsigned pk = cvt_pk(hv0, hv1);
    __hip_atomic_store((unsigned*)(hout + ((long)b_g * 128 + t_io) * 256 + jg0), pk,
                       __ATOMIC_RELAXED, __HIP_MEMORY_SCOPE_AGENT);
    // no drain / no flag: consumers poll the data itself
  }
  if (!last) {
    cstate[(dir * 256 + b_g) * 256 + jg0] = cv0;
    cstate[(dir * 256 + b_g) * 256 + jg0 + 1] = cv1;
  }
}

// ---------- K3: emission  emis[m][16] = [hf|hb] @ W_emit^T + b_emit ----------
__global__ __launch_bounds__(256) void k_emis(const u16* __restrict__ hfb, const u16* __restrict__ hbb,
    const u16* __restrict__ weh, const float* __restrict__ bemit, float* __restrict__ emis) {
  int w = threadIdx.x >> 6, l = threadIdx.x & 63;
  int la = l & 15, lk = (l >> 4) * 8;
  long m0 = (long)blockIdx.x * 64 + w * 16;
  long am = m0 + la;
  f32x4 acc = (f32x4){0.f, 0.f, 0.f, 0.f};
#pragma unroll
  for (int ks = 0; ks < 16; ++ks) {
    int k = ks * 32 + lk;
    const u16* src = (k < 256) ? (hfb + am * 256 + k) : (hbb + am * 256 + (k - 256));
    bf16x8 ah = *(const bf16x8*)src;
    bf16x8 bh = *(const bf16x8*)(weh + la * 512 + k);
    acc = __builtin_amdgcn_mfma_f32_16x16x32_bf16(ah, bh, acc, 0, 0, 0);
  }
  int kout = la;
  float bias = (kout < 9) ? bemit[kout] : 0.f;
  long mr = m0 + (l >> 4) * 4;
#pragma unroll
  for (int r = 0; r < 4; ++r)
    emis[(mr + r) * 16 + kout] = acc[r] + bias;
}

// ---------- K4: CRF forward (logZ) + gold-path numerator ----------
__global__ __launch_bounds__(256) void k_crf(const float* __restrict__ emis, const int* __restrict__ ixin,
    const int* __restrict__ label, const float* __restrict__ startt, const float* __restrict__ endt,
    const float* __restrict__ trans, float* __restrict__ lossp) {
  __shared__ float al_s[16][16];
  __shared__ float tr_s[9][16];
  __shared__ float num_s[16];
  __shared__ float red_s[16];
  int tid = threadIdx.x, bl = tid >> 4, k = tid & 15;
  int b = blockIdx.x * 16 + bl;
  if (bl < 9) tr_s[bl][k] = (k < 9) ? trans[bl * 9 + k] : 0.f;
  float a = 0.f, num = 0.f;
  int lastlab = 0;
  if (k < 9) a = startt[k] + emis[((long)b * 128) * 16 + k];
  al_s[bl][k] = a;
  if (k == 9) {
    int l0 = label[b * 128];
    num = startt[l0] + emis[((long)b * 128) * 16 + l0];
    lastlab = l0;
  }
  __syncthreads();
  for (int t = 1; t < 128; ++t) {
    bool msk = ixin[b * 128 + t] != 0;
    float anew = a;
    if (k < 9) {
      float mx = -1e30f;
#pragma unroll
      for (int j = 0; j < 9; ++j) mx = fmaxf(mx, al_s[bl][j] + tr_s[j][k]);
      float ss = 0.f;
#pragma unroll
      for (int j = 0; j < 9; ++j) ss += __expf(al_s[bl][j] + tr_s[j][k] - mx);
      anew = mx + __logf(ss) + emis[((long)b * 128 + t) * 16 + k];
      if (!msk) anew = a;
    } else if (k == 9 && msk) {
      int lt = label[b * 128 + t];
      num += tr_s[lastlab][lt] + emis[((long)b * 128 + t) * 16 + lt];
      lastlab = lt;
    }
    __syncthreads();
    if (k < 9) { a = anew; al_s[bl][k] = a; }
    __syncthreads();
  }
  if (k == 9) num_s[bl] = num + endt[lastlab];
  __syncthreads();
  if (k == 0) {
    float mx = -1e30f;
#pragma unroll
    for (int j = 0; j < 9; ++j) mx = fmaxf(mx, al_s[bl][j] + endt[j]);
    float ss = 0.f;
#pragma unroll
    for (int j = 0; j < 9; ++j) ss += __expf(al_s[bl][j] + endt[j] - mx);
    red_s[bl] = (mx + __logf(ss)) - num_s[bl];
  }
  __syncthreads();
  if (tid == 0) {
    float s = 0.f;
    for (int i = 0; i < 16; ++i) s += red_s[i];
    lossp[blockIdx.x] = s;
  }
}

// ---------- K5: Viterbi forward storing backpointers ----------
__global__ __launch_bounds__(256) void k_vit(const float* __restrict__ emis,
    const float* __restrict__ startt, const float* __restrict__ trans,
    unsigned char* __restrict__ bp, float* __restrict__ vfin) {
  __shared__ float al_s[16][16];
  __shared__ float tr_s[9][16];
  int tid = threadIdx.x, bl = tid >> 4, k = tid & 15;
  int b = blockIdx.x * 16 + bl;
  if (bl < 9) tr_s[bl][k] = (k < 9) ? trans[bl * 9 + k] : 0.f;
  float v = -1e30f;
  if (k < 9) v = startt[k] + emis[((long)b * 128) * 16 + k];
  al_s[bl][k] = v;
  __syncthreads();
  for (int t = 1; t < 128; ++t) {
    float vnew = v;
    if (k < 9) {
      float best = -1e30f; int bi = 0;
#pragma unroll
      for (int j = 0; j < 9; ++j) {
        float tot = al_s[bl][j] + tr_s[j][k];
        if (tot > best) { best = tot; bi = j; }
      }
      vnew = best + emis[((long)b * 128 + t) * 16 + k];
      bp[((long)b * 127 + (t - 1)) * 16 + k] = (unsigned char)bi;
    }
    __syncthreads();
    if (k < 9) { v = vnew; al_s[bl][k] = v; }
    __syncthreads();
  }
  vfin[b * 16 + k] = (k < 9) ? v : -1e30f;
}

// ---------- K6: backtrace (LDS-staged) + loss reduction ----------
__global__ __launch_bounds__(256) void k_fin(const float* __restrict__ vfin, const float* __restrict__ endt,
    const unsigned char* __restrict__ bp, const float* __restrict__ lossp, float* __restrict__ out) {
  __shared__ unsigned char bpl[16 * 127 * 16];
  int tid = threadIdx.x;
  const unsigned* src = (const unsigned*)(bp + (long)blockIdx.x * 32512);
  unsigned* dst = (unsigned*)bpl;
  for (int i = tid; i < 8128; i += 256) dst[i] = src[i];
  __syncthreads();
  if (tid < 16) {
    int b = blockIdx.x * 16 + tid;
    float best = -1e30f; int tag = 0;
#pragma unroll
    for (int j = 0; j < 9; ++j) {
      float v = vfin[b * 16 + j] + endt[j];
      if (v > best) { best = v; tag = j; }
    }
    out[1 + b * 128 + 127] = (float)tag;
    for (int t = 127; t >= 1; --t) {
      tag = bpl[(tid * 127 + (t - 1)) * 16 + tag];
      out[1 + b * 128 + t - 1] = (float)tag;
    }
  }
  if (blockIdx.x == 0 && tid == 0) {
    float s = 0.f;
    for (int i = 0; i < 16; ++i) s += lossp[i];
    out[0] = s;
  }
}

__global__ void k_sent(float* out) { out[0] = -1.0e6f; }

// ---------- launch ----------
extern "C" void kernel_launch(void* const* d_in, const int* in_sizes, int n_in,
                              void* d_out, int out_size, void* d_ws, size_t ws_size,
                              hipStream_t stream) {
  const int* in_x    = (const int*)d_in[0];
  const int* label   = (const int*)d_in[1];
  const float* emb   = (const float*)d_in[2];
  const float* Wih_f = (const float*)d_in[3];
  const float* Whh_f = (const float*)d_in[4];
  const float* b_f   = (const float*)d_in[5];
  const float* Wih_b = (const float*)d_in[6];
  const float* Whh_b = (const float*)d_in[7];
  const float* b_b   = (const float*)d_in[8];
  const float* W_emit= (const float*)d_in[9];
  const float* b_emit= (const float*)d_in[10];
  const float* start_t=(const float*)d_in[11];
  const float* end_t = (const float*)d_in[12];
  const float* trans = (const float*)d_in[13];
  const float* h0f   = (const float*)d_in[14];
  const float* c0f   = (const float*)d_in[15];
  const float* h0b   = (const float*)d_in[16];
  const float* c0b   = (const float*)d_in[17];
  (void)in_sizes; (void)n_in; (void)out_size;

  auto align = [](size_t x) { return (x + 255) & ~(size_t)255; };
  size_t fixed = 0;
  fixed += align(32768L * 256 * 2);   // HF bf16
  fixed += align(32768L * 256 * 2);   // HB bf16
  fixed += align(30000L * 256 * 2);   // EBH
  fixed += align(2048L * 256 * 2);    // WIHH
  fixed += align(16L * 512 * 2);      // WEH
  fixed += align(32768L * 16 * 4);    // EMIS
  fixed += align(256L * 127 * 16);    // BP
  fixed += align(256L * 16 * 4);      // VFIN
  fixed += align(64 * 4);             // LOSSP
  fixed += align(2L * 256 * 256 * 4); // CSTATE

  int S = 0;
  const int cands[4] = {128, 64, 32, 16};
  for (int ci = 0; ci < 4; ++ci) {
    size_t xb = align(1048576L * cands[ci]);   // xw bf16: 2*256*S*1024*2B
    if (xb + fixed <= ws_size) { S = cands[ci]; break; }
  }
  if (S == 0) { k_sent<<<1, 1, 0, stream>>>((float*)d_out); return; }
  int logS = __builtin_ctz(S);
  int NC = 128 / S;

  char* ws = (char*)d_ws;
  size_t o = 0;
  auto alloc = [&](size_t sz) { size_t r = o; o += (sz + 255) & ~(size_t)255; return r; };
  u16* xw    = (u16*)(ws + alloc(1048576L * S));
  u16* hf    = (u16*)(ws + alloc(32768L * 256 * 2));
  u16* hb    = (u16*)(ws + alloc(32768L * 256 * 2));
  u16* ebh   = (u16*)(ws + alloc(30000L * 256 * 2));
  u16* wihh  = (u16*)(ws + alloc(2048L * 256 * 2));
  u16* weh   = (u16*)(ws + alloc(16L * 512 * 2));
  float* emis= (float*)(ws + alloc(32768L * 16 * 4));
  unsigned char* bp = (unsigned char*)(ws + alloc(256L * 127 * 16));
  float* vfin = (float*)(ws + alloc(256L * 16 * 4));
  float* lossp= (float*)(ws + alloc(64 * 4));
  float* cstate = (float*)(ws + alloc(2L * 256 * 256 * 4));

  // sentinel-init h buffers (0xC1C1 bf16 == -24.1, impossible for tanh*sigm)
  hipMemsetAsync(hf, 0xC1, 32768L * 256 * 2, stream);
  hipMemsetAsync(hb, 0xC1, 32768L * 256 * 2, stream);
  k_prep<<<8020, 256, 0, stream>>>(emb, Wih_f, Wih_b, W_emit, ebh, wihh, weh);
  for (int c = 0; c < NC; ++c) {
    k_gemm_in<<<dim3(2 * S, 8, 2), 256, 0, stream>>>(in_x, ebh, wihh, b_f, b_b,
                                                     xw, c * S, S, logS);
    k_lstm<<<256, 256, 0, stream>>>(Whh_f, Whh_b, h0f, c0f, h0b, c0b, xw, hf, hb,
                                    cstate, c * S, S, c == 0 ? 1 : 0, c == NC - 1 ? 1 : 0);
  }
  k_emis<<<512, 256, 0, stream>>>(hf, hb, weh, b_emit, emis);
  k_crf<<<16, 256, 0, stream>>>(emis, in_x, label, start_t, end_t, trans, lossp);
  k_vit<<<16, 256, 0, stream>>>(emis, start_t, trans, bp, vfin);
  k_fin<<<16, 256, 0, stream>>>(vfin, end_t, bp, lossp, (float*)d_out);
}

// Round 7
// 443.137 us; speedup vs baseline: 6.9069x; 1.1127x over previous
//
#include <hip/hip_runtime.h>

typedef __attribute__((ext_vector_type(8))) short bf16x8;
typedef __attribute__((ext_vector_type(4))) float f32x4;
typedef __attribute__((ext_vector_type(4))) unsigned u32x4;
typedef unsigned short u16;

#define SENT 0xC1C1C1C1u

// ---------- helpers ----------
__device__ __forceinline__ u16 f2bf(float f) {
  union { float f; unsigned u; } v; v.f = f;
  unsigned r = v.u + 0x7fffu + ((v.u >> 16) & 1u);
  return (u16)(r >> 16);
}
__device__ __forceinline__ unsigned cvt_pk(float lo, float hi) {
  unsigned r;
  asm("v_cvt_pk_bf16_f32 %0, %1, %2" : "=v"(r) : "v"(lo), "v"(hi));
  return r;
}
__device__ __forceinline__ float bflo(unsigned d) { return __uint_as_float(d << 16); }
__device__ __forceinline__ float bfhi(unsigned d) { return __uint_as_float(d & 0xffff0000u); }
__device__ __forceinline__ float sigm(float x) { return 1.f / (1.f + __expf(-x)); }
__device__ __forceinline__ float tanhf_(float x) { return 1.f - 2.f / (__expf(2.f * x) + 1.f); }

// ---------- K0: one-pass f32 -> bf16 prep (emb | Wih f,b | W_emit padded) ----------
__global__ __launch_bounds__(256) void k_prep(const float* __restrict__ emb,
    const float* __restrict__ wf, const float* __restrict__ wb, const float* __restrict__ we,
    u16* __restrict__ ebh, u16* __restrict__ wihh, u16* __restrict__ weh) {
  int i4 = (blockIdx.x * 256 + threadIdx.x) * 4;
  const float* src; u16* dst; int o;
  bool zero = false;
  if (i4 < 7680000) { src = emb + i4; dst = ebh; o = i4; }
  else if (i4 < 8204288) {
    int off = i4 - 7680000;
    src = (off < 262144) ? (wf + off) : (wb + off - 262144);
    dst = wihh; o = off;
  } else {
    int off = i4 - 8204288;
    int r = off >> 9, k = off & 511;
    dst = weh; o = off;
    if (r < 9) src = we + r * 512 + k; else { zero = true; src = we; }
  }
  f32x4 v = zero ? (f32x4){0.f, 0.f, 0.f, 0.f} : *(const f32x4*)src;
  *(unsigned*)(dst + o) = cvt_pk(v[0], v[1]);
  *(unsigned*)(dst + o + 2) = cvt_pk(v[2], v[3]);
}

// ---------- K1: chunked input GEMM (bf16, B tile LDS-staged with XOR swizzle) ----------
__global__ __launch_bounds__(256) void k_gemm_in(const int* __restrict__ ix,
    const u16* __restrict__ ebh, const u16* __restrict__ wihh,
    const float* __restrict__ bf_, const float* __restrict__ bb_,
    u16* __restrict__ xw, int c0step, int S, int logS) {
  __shared__ __align__(16) char smraw[128 * 132 * 4];
  int tid = threadIdx.x;
  int w = tid >> 6, l = tid & 63, la = l & 15, lk = (l >> 4) * 8;
  int dir = blockIdx.z;
  int m0 = blockIdx.x * 128;
  int n0 = blockIdx.y * 128;
  const char* gB = (const char*)(wihh + ((long)(dir * 1024 + n0) << 8));
#pragma unroll
  for (int it = 0; it < 16; ++it) {
    int y = it * 4096 + tid * 16;
    int sw = y ^ (((y >> 9) & 7) << 4);
    *(u32x4*)(smraw + sw) = *(const u32x4*)(gB + y);
  }
  long arow[2];
#pragma unroll
  for (int mf = 0; mf < 2; ++mf) {
    int mA = m0 + w * 32 + mf * 16 + la;
    int bA = mA >> logS, slA = mA & (S - 1);
    int sg = c0step + slA;
    int tA = dir ? (127 - sg) : sg;
    arow[mf] = (long)ix[bA * 128 + tA] << 8;
  }
  int gb[8], gx[8];
#pragma unroll
  for (int nt = 0; nt < 8; ++nt) { int g = nt * 16 + la; gb[nt] = g * 512; gx[nt] = (g & 7) << 4; }
  __syncthreads();
  f32x4 acc[2][8];
#pragma unroll
  for (int mf = 0; mf < 2; ++mf)
#pragma unroll
    for (int nt = 0; nt < 8; ++nt) acc[mf][nt] = (f32x4){0.f, 0.f, 0.f, 0.f};
#pragma unroll
  for (int ks = 0; ks < 8; ++ks) {
    int k = ks * 32 + lk;
    int kb = 2 * k;
    bf16x8 a0 = *(const bf16x8*)(ebh + arow[0] + k);
    bf16x8 a1 = *(const bf16x8*)(ebh + arow[1] + k);
#pragma unroll
    for (int nt = 0; nt < 8; ++nt) {
      bf16x8 bh = *(const bf16x8*)(smraw + gb[nt] + (kb ^ gx[nt]));
      acc[0][nt] = __builtin_amdgcn_mfma_f32_16x16x32_bf16(a0, bh, acc[0][nt], 0, 0, 0);
      acc[1][nt] = __builtin_amdgcn_mfma_f32_16x16x32_bf16(a1, bh, acc[1][nt], 0, 0, 0);
    }
  }
  __syncthreads();
  float* ot = (float*)smraw;
#pragma unroll
  for (int mf = 0; mf < 2; ++mf)
#pragma unroll
    for (int nt = 0; nt < 8; ++nt)
#pragma unroll
      for (int r = 0; r < 4; ++r)
        ot[(w * 32 + mf * 16 + (l >> 4) * 4 + r) * 132 + nt * 16 + la] = acc[mf][nt][r];
  __syncthreads();
  const float* bias = (dir ? bb_ : bf_) + n0;
  long MSd = (long)256 * S * 1024;
  int m_r0 = tid >> 4;
  int cc = (tid & 15) * 8;
  f32x4 b0 = *(const f32x4*)(bias + cc);
  f32x4 b1 = *(const f32x4*)(bias + cc + 4);
#pragma unroll
  for (int it = 0; it < 8; ++it) {
    int m_r = it * 16 + m_r0;
    f32x4 v0 = *(const f32x4*)&ot[m_r * 132 + cc];
    f32x4 v1 = *(const f32x4*)&ot[m_r * 132 + cc + 4];
    u32x4 q;
    q[0] = cvt_pk(v0[0] + b0[0], v0[1] + b0[1]);
    q[1] = cvt_pk(v0[2] + b0[2], v0[3] + b0[3]);
    q[2] = cvt_pk(v1[0] + b1[0], v1[1] + b1[1]);
    q[3] = cvt_pk(v1[2] + b1[2], v1[3] + b1[3]);
    *(u32x4*)(xw + dir * MSd + (long)(m0 + m_r) * 1024 + n0 + cc) = q;
  }
}

// ---------- K2: BiLSTM recurrence, sentinel-dataflow cross-block sync (round-5 proven) ----------
#define LW 264
__global__ __launch_bounds__(256) void k_lstm(
    const float* __restrict__ whh_f, const float* __restrict__ whh_b,
    const float* __restrict__ h0f, const float* __restrict__ c0f,
    const float* __restrict__ h0b, const float* __restrict__ c0b,
    const u16* __restrict__ xwp,
    u16* __restrict__ hf, u16* __restrict__ hb,
    float* __restrict__ cstate,
    int s0, int S, int first, int last) {
  __shared__ u16 wlh[128 * LW];
  __shared__ u16 hst[16 * LW];
  __shared__ float gl[16 * 132];
  int bid = blockIdx.x;
  int js = (bid >> 3) & 7;
  int G = ((bid >> 6) << 3) | (bid & 7);
  int dir = G >> 4, bs = G & 15;
  const float* whh = dir ? whh_b : whh_f;
  u16* hout = dir ? hb : hf;
  int tid = threadIdx.x;
  for (int i = 0; i < 128; ++i) {
    int q = i >> 5, u = i & 31;
    int gate = q * 256 + js * 32 + u;
    wlh[i * LW + tid] = f2bf(whh[gate * 256 + tid]);
  }
  int b_l = tid >> 4, jj = tid & 15;
  int b_g = bs * 16 + b_l;
  int jg0 = js * 32 + jj * 2;
  float cv0, cv1;
  if (first) {
    const float* c0 = dir ? c0b : c0f;
    cv0 = c0[b_g * 256 + jg0];
    cv1 = c0[b_g * 256 + jg0 + 1];
  } else {
    cv0 = cstate[(dir * 256 + b_g) * 256 + jg0];
    cv1 = cstate[(dir * 256 + b_g) * 256 + jg0 + 1];
  }
  int w = tid >> 6, l = tid & 63, la = l & 15, lk = (l >> 4) * 8;
  int srow = tid >> 4, scol = (tid & 15) * 16;
  const float* h0 = dir ? h0b : h0f;
  long MSd = (long)256 * S * 1024;
  __syncthreads();
  for (int sl = 0; sl < S; ++sl) {
    int sg = s0 + sl;
    int t_io = dir ? 127 - sg : sg;
    long xbase = (long)dir * MSd + ((long)b_g * S + sl) * 1024 + jg0;
    unsigned dI = *(const unsigned*)(xwp + xbase);
    unsigned dF = *(const unsigned*)(xwp + xbase + 256);
    unsigned dG = *(const unsigned*)(xwp + xbase + 512);
    unsigned dO = *(const unsigned*)(xwp + xbase + 768);
    u16* hd = &hst[srow * LW + scol];
    if (sg == 0) {
      const float* p = h0 + (bs * 16 + srow) * 256 + scol;
      f32x4 v0 = *(const f32x4*)p, v1 = *(const f32x4*)(p + 4);
      f32x4 v2 = *(const f32x4*)(p + 8), v3 = *(const f32x4*)(p + 12);
      u32x4 qa, qb;
      qa[0] = cvt_pk(v0[0], v0[1]); qa[1] = cvt_pk(v0[2], v0[3]);
      qa[2] = cvt_pk(v1[0], v1[1]); qa[3] = cvt_pk(v1[2], v1[3]);
      qb[0] = cvt_pk(v2[0], v2[1]); qb[1] = cvt_pk(v2[2], v2[3]);
      qb[2] = cvt_pk(v3[0], v3[1]); qb[3] = cvt_pk(v3[2], v3[3]);
      *(u32x4*)hd = qa; *((u32x4*)hd + 1) = qb;
    } else {
      int tp = dir ? t_io + 1 : t_io - 1;
      const u16* p = hout + ((long)(bs * 16 + srow) * 128 + tp) * 256 + scol;
      u32x4 r0, r1; int guard = 0; bool ok;
      do {
        asm volatile(
          "global_load_dwordx4 %0, %2, off sc0 sc1\n\t"
          "global_load_dwordx4 %1, %2, off offset:16 sc0 sc1\n\t"
          "s_waitcnt vmcnt(0)"
          : "=v"(r0), "=v"(r1) : "v"(p) : "memory");
        ok = (r0[0] != SENT) & (r0[1] != SENT) & (r0[2] != SENT) & (r0[3] != SENT)
           & (r1[0] != SENT) & (r1[1] != SENT) & (r1[2] != SENT) & (r1[3] != SENT);
      } while (__builtin_expect(!ok, 0) && ++guard < (1 << 22));
      *(u32x4*)hd = r0; *((u32x4*)hd + 1) = r1;
    }
    __syncthreads();
    f32x4 a0 = (f32x4){0.f, 0.f, 0.f, 0.f}, a1 = (f32x4){0.f, 0.f, 0.f, 0.f};
#pragma unroll
    for (int ks = 0; ks < 8; ++ks) {
      int k = ks * 32 + lk;
      bf16x8 ah = *(const bf16x8*)&hst[la * LW + k];
      bf16x8 b0 = *(const bf16x8*)&wlh[(w * 32 + la) * LW + k];
      bf16x8 b1 = *(const bf16x8*)&wlh[(w * 32 + 16 + la) * LW + k];
      a0 = __builtin_amdgcn_mfma_f32_16x16x32_bf16(ah, b0, a0, 0, 0, 0);
      a1 = __builtin_amdgcn_mfma_f32_16x16x32_bf16(ah, b1, a1, 0, 0, 0);
    }
#pragma unroll
    for (int r = 0; r < 4; ++r) {
      gl[((l >> 4) * 4 + r) * 132 + w * 32 + la] = a0[r];
      gl[((l >> 4) * 4 + r) * 132 + w * 32 + 16 + la] = a1[r];
    }
    __syncthreads();
    float hv0, hv1;
    {
      int jl = jj * 2;
      float gi = gl[b_l * 132 + jl]      + bflo(dI);
      float gf = gl[b_l * 132 + 32 + jl] + bflo(dF);
      float gg = gl[b_l * 132 + 64 + jl] + bflo(dG);
      float go = gl[b_l * 132 + 96 + jl] + bflo(dO);
      float c = sigm(gf) * cv0 + sigm(gi) * tanhf_(gg);
      cv0 = c; hv0 = sigm(go) * tanhf_(c);
    }
    {
      int jl = jj * 2 + 1;
      float gi = gl[b_l * 132 + jl]      + bfhi(dI);
      float gf = gl[b_l * 132 + 32 + jl] + bfhi(dF);
      float gg = gl[b_l * 132 + 64 + jl] + bfhi(dG);
      float go = gl[b_l * 132 + 96 + jl] + bfhi(dO);
      float c = sigm(gf) * cv1 + sigm(gi) * tanhf_(gg);
      cv1 = c; hv1 = sigm(go) * tanhf_(c);
    }
    unsigned pk = cvt_pk(hv0, hv1);
    __hip_atomic_store((unsigned*)(hout + ((long)b_g * 128 + t_io) * 256 + jg0), pk,
                       __ATOMIC_RELAXED, __HIP_MEMORY_SCOPE_AGENT);
  }
  if (!last) {
    cstate[(dir * 256 + b_g) * 256 + jg0] = cv0;
    cstate[(dir * 256 + b_g) * 256 + jg0 + 1] = cv1;
  }
}

// ---------- K3: emission (also zero-inits out[0] for the tail's atomic loss sum) ----------
__global__ __launch_bounds__(256) void k_emis(const u16* __restrict__ hfb, const u16* __restrict__ hbb,
    const u16* __restrict__ weh, const float* __restrict__ bemit, float* __restrict__ emis,
    float* __restrict__ out) {
  if (blockIdx.x == 0 && threadIdx.x == 0) out[0] = 0.f;
  int w = threadIdx.x >> 6, l = threadIdx.x & 63;
  int la = l & 15, lk = (l >> 4) * 8;
  long m0 = (long)blockIdx.x * 64 + w * 16;
  long am = m0 + la;
  f32x4 acc = (f32x4){0.f, 0.f, 0.f, 0.f};
#pragma unroll
  for (int ks = 0; ks < 16; ++ks) {
    int k = ks * 32 + lk;
    const u16* src = (k < 256) ? (hfb + am * 256 + k) : (hbb + am * 256 + (k - 256));
    bf16x8 ah = *(const bf16x8*)src;
    bf16x8 bh = *(const bf16x8*)(weh + la * 512 + k);
    acc = __builtin_amdgcn_mfma_f32_16x16x32_bf16(ah, bh, acc, 0, 0, 0);
  }
  int kout = la;
  float bias = (kout < 9) ? bemit[kout] : 0.f;
  long mr = m0 + (l >> 4) * 4;
#pragma unroll
  for (int r = 0; r < 4; ++r)
    emis[(mr + r) * 16 + kout] = acc[r] + bias;
}

// ---------- K4: fused tail. Blocks 0-15: CRF -> atomicAdd loss into out[0].
//                          Blocks 16-31: Viterbi (LDS backpointers) + backtrace. ----------
__global__ __launch_bounds__(256) void k_tail(const float* __restrict__ emis, const int* __restrict__ ixin,
    const int* __restrict__ label, const float* __restrict__ startt, const float* __restrict__ endt,
    const float* __restrict__ trans, float* __restrict__ out) {
  __shared__ float al_s[16][16];
  __shared__ float tr_s[9][16];
  __shared__ float num_s[16];
  __shared__ float red_s[16];
  __shared__ unsigned char bpl[16 * 127 * 16];
  int tid = threadIdx.x, bl = tid >> 4, k = tid & 15;
  int bid = blockIdx.x;
  if (bl < 9) tr_s[bl][k] = (k < 9) ? trans[bl * 9 + k] : 0.f;
  if (bid < 16) {
    int b = bid * 16 + bl;
    float a = 0.f, num = 0.f;
    int lastlab = 0;
    if (k < 9) a = startt[k] + emis[((long)b * 128) * 16 + k];
    al_s[bl][k] = a;
    if (k == 9) {
      int l0 = label[b * 128];
      num = startt[l0] + emis[((long)b * 128) * 16 + l0];
      lastlab = l0;
    }
    __syncthreads();
    for (int t = 1; t < 128; ++t) {
      bool msk = ixin[b * 128 + t] != 0;
      float anew = a;
      if (k < 9) {
        float mx = -1e30f;
#pragma unroll
        for (int j = 0; j < 9; ++j) mx = fmaxf(mx, al_s[bl][j] + tr_s[j][k]);
        float ss = 0.f;
#pragma unroll
        for (int j = 0; j < 9; ++j) ss += __expf(al_s[bl][j] + tr_s[j][k] - mx);
        anew = mx + __logf(ss) + emis[((long)b * 128 + t) * 16 + k];
        if (!msk) anew = a;
      } else if (k == 9 && msk) {
        int lt = label[b * 128 + t];
        num += tr_s[lastlab][lt] + emis[((long)b * 128 + t) * 16 + lt];
        lastlab = lt;
      }
      __syncthreads();
      if (k < 9) { a = anew; al_s[bl][k] = a; }
      __syncthreads();
    }
    if (k == 9) num_s[bl] = num + endt[lastlab];
    __syncthreads();
    if (k == 0) {
      float mx = -1e30f;
#pragma unroll
      for (int j = 0; j < 9; ++j) mx = fmaxf(mx, al_s[bl][j] + endt[j]);
      float ss = 0.f;
#pragma unroll
      for (int j = 0; j < 9; ++j) ss += __expf(al_s[bl][j] + endt[j] - mx);
      red_s[bl] = (mx + __logf(ss)) - num_s[bl];
    }
    __syncthreads();
    if (tid == 0) {
      float s = 0.f;
      for (int i = 0; i < 16; ++i) s += red_s[i];
      atomicAdd(out, s);
    }
  } else {
    int vb = bid - 16;
    int b = vb * 16 + bl;
    float v = -1e30f;
    if (k < 9) v = startt[k] + emis[((long)b * 128) * 16 + k];
    al_s[bl][k] = v;
    __syncthreads();
    for (int t = 1; t < 128; ++t) {
      float vnew = v;
      if (k < 9) {
        float best = -1e30f; int bi = 0;
#pragma unroll
        for (int j = 0; j < 9; ++j) {
          float tot = al_s[bl][j] + tr_s[j][k];
          if (tot > best) { best = tot; bi = j; }
        }
        vnew = best + emis[((long)b * 128 + t) * 16 + k];
        bpl[(bl * 127 + (t - 1)) * 16 + k] = (unsigned char)bi;
      }
      __syncthreads();
      if (k < 9) { v = vnew; al_s[bl][k] = v; }
      __syncthreads();
    }
    if (tid < 16) {
      int bb = vb * 16 + tid;
      float best = -1e30f; int tag = 0;
#pragma unroll
      for (int j = 0; j < 9; ++j) {
        float vv = al_s[tid][j] + endt[j];
        if (vv > best) { best = vv; tag = j; }
      }
      out[1 + bb * 128 + 127] = (float)tag;
      for (int t = 127; t >= 1; --t) {
        tag = bpl[(tid * 127 + (t - 1)) * 16 + tag];
        out[1 + bb * 128 + t - 1] = (float)tag;
      }
    }
  }
}

__global__ void k_sent(float* out) { out[0] = -1.0e6f; }

// ---------- launch ----------
extern "C" void kernel_launch(void* const* d_in, const int* in_sizes, int n_in,
                              void* d_out, int out_size, void* d_ws, size_t ws_size,
                              hipStream_t stream) {
  const int* in_x    = (const int*)d_in[0];
  const int* label   = (const int*)d_in[1];
  const float* emb   = (const float*)d_in[2];
  const float* Wih_f = (const float*)d_in[3];
  const float* Whh_f = (const float*)d_in[4];
  const float* b_f   = (const float*)d_in[5];
  const float* Wih_b = (const float*)d_in[6];
  const float* Whh_b = (const float*)d_in[7];
  const float* b_b   = (const float*)d_in[8];
  const float* W_emit= (const float*)d_in[9];
  const float* b_emit= (const float*)d_in[10];
  const float* start_t=(const float*)d_in[11];
  const float* end_t = (const float*)d_in[12];
  const float* trans = (const float*)d_in[13];
  const float* h0f   = (const float*)d_in[14];
  const float* c0f   = (const float*)d_in[15];
  const float* h0b   = (const float*)d_in[16];
  const float* c0b   = (const float*)d_in[17];
  (void)in_sizes; (void)n_in; (void)out_size;

  auto align = [](size_t x) { return (x + 255) & ~(size_t)255; };
  size_t fixed = 0;
  fixed += align(32768L * 256 * 2);   // HF bf16
  fixed += align(32768L * 256 * 2);   // HB bf16
  fixed += align(30000L * 256 * 2);   // EBH
  fixed += align(2048L * 256 * 2);    // WIHH
  fixed += align(16L * 512 * 2);      // WEH
  fixed += align(32768L * 16 * 4);    // EMIS
  fixed += align(2L * 256 * 256 * 4); // CSTATE

  int S = 0;
  const int cands[4] = {128, 64, 32, 16};
  for (int ci = 0; ci < 4; ++ci) {
    size_t xb = align(1048576L * cands[ci]);
    if (xb + fixed <= ws_size) { S = cands[ci]; break; }
  }
  if (S == 0) { k_sent<<<1, 1, 0, stream>>>((float*)d_out); return; }
  int logS = __builtin_ctz(S);
  int NC = 128 / S;

  char* ws = (char*)d_ws;
  size_t o = 0;
  auto alloc = [&](size_t sz) { size_t r = o; o += (sz + 255) & ~(size_t)255; return r; };
  u16* xw    = (u16*)(ws + alloc(1048576L * S));
  u16* hf    = (u16*)(ws + alloc(32768L * 256 * 2));
  u16* hb    = (u16*)(ws + alloc(32768L * 256 * 2));
  u16* ebh   = (u16*)(ws + alloc(30000L * 256 * 2));
  u16* wihh  = (u16*)(ws + alloc(2048L * 256 * 2));
  u16* weh   = (u16*)(ws + alloc(16L * 512 * 2));
  float* emis= (float*)(ws + alloc(32768L * 16 * 4));
  float* cstate = (float*)(ws + alloc(2L * 256 * 256 * 4));

  // sentinel-init h buffers (0xC1C1 bf16 == -24.1, impossible for tanh*sigm output)
  hipMemsetAsync(hf, 0xC1, 32768L * 256 * 2, stream);
  hipMemsetAsync(hb, 0xC1, 32768L * 256 * 2, stream);
  k_prep<<<8020, 256, 0, stream>>>(emb, Wih_f, Wih_b, W_emit, ebh, wihh, weh);
  for (int c = 0; c < NC; ++c) {
    k_gemm_in<<<dim3(2 * S, 8, 2), 256, 0, stream>>>(in_x, ebh, wihh, b_f, b_b,
                                                     xw, c * S, S, logS);
    k_lstm<<<256, 256, 0, stream>>>(Whh_f, Whh_b, h0f, c0f, h0b, c0b, xw, hf, hb,
                                    cstate, c * S, S, c == 0 ? 1 : 0, c == NC - 1 ? 1 : 0);
  }
  k_emis<<<512, 256, 0, stream>>>(hf, hb, weh, b_emit, emis, (float*)d_out);
  k_tail<<<32, 256, 0, stream>>>(emis, in_x, label, start_t, end_t, trans, (float*)d_out);
}